// Round 7
// baseline (1364.179 us; speedup 1.0000x reference)
//
#include <hip/hip_runtime.h>
#include <math.h>

constexpr int B_  = 2;
constexpr int T_  = 2048;
constexpr int D_  = 512;
constexpr int NH_ = 8;
constexpr int NL_ = 256;
constexpr int HN_ = NH_ * NL_;   // 2048
constexpr int BT_ = B_ * T_;     // 4096
constexpr int SLP = 136;         // padded Sl row (272 B = 17*16, b128-aligned)

typedef __bf16 v8bf __attribute__((ext_vector_type(8)));
typedef float  v4f  __attribute__((ext_vector_type(4)));
typedef unsigned short us8 __attribute__((ext_vector_type(8)));

__device__ inline unsigned short f2b(float f) {
    union { float f; unsigned u; } v{f};
    unsigned r = v.u + 0x7FFF + ((v.u >> 16) & 1);   // rtne
    return (unsigned short)(r >> 16);
}
__device__ inline float b2f(unsigned short u) {
    union { unsigned u; float f; } v{(unsigned)u << 16};
    return v.f;
}

// async 16B global->LDS (per-lane gaddr; LDS dest = wave-uniform base + lane*16)
__device__ __forceinline__ void g2l16(const void* g, void* l) {
    __builtin_amdgcn_global_load_lds(
        (const __attribute__((address_space(1))) void*)g,
        (__attribute__((address_space(3))) void*)l, 16, 0, 0);
}

// ===========================================================================
// 64x128-tile core ids (generic GEMM): 4 waves n-split 32, 4x2 MFMA.
#define T64_IDS                                               \
    int tid = threadIdx.x;                                    \
    int lane = tid & 63, wid = tid >> 6;                      \
    int wn = wid * 32;                                        \
    int ln16 = lane & 15, q = lane >> 4;                      \
    int srl = lane >> 2, scl = (lane & 3) * 8;

#define T64_STAGE(Ab, lda, Bb, ldb, k0)                       \
    _Pragma("unroll")                                         \
    for (int ci = 0; ci < 3; ++ci) {                          \
        int c = wid * 3 + ci;                                 \
        if (c < 4) {                                          \
            int r = c * 16 + srl;                             \
            g2l16(Ab + (long)r * lda + (k0) + scl, (char*)As + c * 1024); \
        } else {                                              \
            int r = (c - 4) * 16 + srl;                       \
            g2l16(Bb + (long)r * ldb + (k0) + scl, (char*)Bs + (c - 4) * 1024); \
        }                                                     \
    }

#define T64_MFMA(As, Bs)                                      \
    {                                                         \
        v8bf af[4], bf2[2];                                   \
        _Pragma("unroll")                                     \
        for (int r = 0; r < 4; ++r)                           \
            af[r] = *(const v8bf*)&As[r * 16 + ln16][q * 8];  \
        _Pragma("unroll")                                     \
        for (int c = 0; c < 2; ++c)                           \
            bf2[c] = *(const v8bf*)&Bs[wn + c * 16 + ln16][q * 8]; \
        _Pragma("unroll")                                     \
        for (int r = 0; r < 4; ++r)                           \
            _Pragma("unroll")                                 \
            for (int c = 0; c < 2; ++c)                       \
                acc[r][c] = __builtin_amdgcn_mfma_f32_16x16x32_bf16( \
                    af[r], bf2[c], acc[r][c], 0, 0, 0);       \
    }

// ---------------------------------------------------------------------------
// Generic 64-row bf16 GEMM: C[M,N] = A[M,K] @ Bt[N,K]^T, z-batched (split-K
// via sA/sB element offsets + sC output slices; per-head via matrix strides).
template <bool RELU, bool MUL, bool BF16OUT>
__global__ __launch_bounds__(256) void gemm64(
    const unsigned short* __restrict__ A, int lda, long sA,
    const unsigned short* __restrict__ Bt, int ldb, long sB,
    void* __restrict__ Cv, int ldc, long sC,
    const unsigned short* __restrict__ mulp, int M, int N, int K) {
    int m0 = blockIdx.y * 64, n0 = blockIdx.x * 128, z = blockIdx.z;
    __shared__ unsigned short As[64][32];    // 4 KB
    __shared__ unsigned short Bs[128][32];   // 8 KB
    const unsigned short* Ab = A  + (long)z * sA + (long)m0 * lda;
    const unsigned short* Bb = Bt + (long)z * sB + (long)n0 * ldb;
    T64_IDS
    v4f acc[4][2] = {};
    for (int k0 = 0; k0 < K; k0 += 32) {
        T64_STAGE(Ab, lda, Bb, ldb, k0)
        __syncthreads();
        T64_MFMA(As, Bs)
        __syncthreads();
    }
    float* Cf = (float*)Cv;
    unsigned short* Cb = (unsigned short*)Cv;
    long zoff = (long)z * sC;
    #pragma unroll
    for (int r = 0; r < 4; ++r)
        #pragma unroll
        for (int c = 0; c < 2; ++c)
            #pragma unroll
            for (int e = 0; e < 4; ++e) {
                int row = m0 + r * 16 + q * 4 + e;
                int col = n0 + wn + c * 16 + ln16;
                float v = acc[r][c][e];
                if (RELU) v = fmaxf(v, 0.f);
                long idx = zoff + (long)row * ldc + col;
                if (MUL) v *= b2f(mulp[idx]);
                if (BF16OUT) Cb[idx] = f2b(v);
                else         Cf[idx] = v;
            }
}

// ---------------------------------------------------------------------------
// Fused flash-style attention: yKV = strict_tril(QR QR^T) @ xs, S never hits
// HBM.  grid (2 Dchunk, 32 Qtile64, 16 z=b*8+h), heavy-first in y.
// Per j-tile (j <= iq/2): S(64x128) via MFMA from QR (L2-hot), mask on the
// single overlap tile, C-layout -> LDS Sl -> A-operand layout (m120 pattern),
// then Y(64x256) += S @ X with X staged from xsT [b][d][t] (K-major).
__global__ __launch_bounds__(256, 3) void attn_fused(
    const unsigned short* __restrict__ qr,   // [B][NH][T][NL]
    const unsigned short* __restrict__ xsT,  // [B][D][T]
    unsigned short* __restrict__ ykv) {      // [NH][BT][D]
    __shared__ unsigned short As[64][32];    //  4 KB  QR_i k-chunk
    __shared__ unsigned short Bs[128][32];   //  8 KB  QR_j k-chunk
    __shared__ unsigned short Xs[256][32];   // 16 KB  X k-chunk
    __shared__ unsigned short Sl[64][SLP];   // 17 KB  S tile (padded)
    int dc = blockIdx.x;                 // D-chunk of 256
    int iq = 31 - blockIdx.y;            // 64-row Q tile, heavy first
    int z  = blockIdx.z;
    int b = z >> 3, h = z & 7;
    const unsigned short* Qi = qr + ((long)z * T_ + iq * 64) * NL_;
    const unsigned short* Qz = qr + (long)z * T_ * NL_;
    const unsigned short* Xb = xsT + (long)b * D_ * T_ + (long)(dc * 256) * T_;
    int tid = threadIdx.x;
    int lane = tid & 63, wid = tid >> 6;
    int ln16 = lane & 15, q = lane >> 4;
    int srl = lane >> 2, scl = (lane & 3) * 8;
    v4f yacc[4][4] = {};
    int jmax = iq >> 1;
    for (int j = 0; j <= jmax; ++j) {
        const unsigned short* Qj = Qz + (long)j * 128 * NL_;
        // ---- S phase: S[64x128] = QR_i @ QR_j^T over NL=256 ----
        v4f sacc[4][2] = {};
        for (int k8 = 0; k8 < 8; ++k8) {
            int kk = k8 * 32;
            #pragma unroll
            for (int ci = 0; ci < 3; ++ci) {          // 12 chunks, 3/wave
                int c = wid * 3 + ci;
                if (c < 4) {
                    int r = c * 16 + srl;
                    g2l16(Qi + (long)r * NL_ + kk + scl, (char*)As + c * 1024);
                } else {
                    int r = (c - 4) * 16 + srl;
                    g2l16(Qj + (long)r * NL_ + kk + scl,
                          (char*)Bs + (c - 4) * 1024);
                }
            }
            __syncthreads();
            v8bf af[4], bf2[2];
            #pragma unroll
            for (int r = 0; r < 4; ++r)
                af[r] = *(const v8bf*)&As[r * 16 + ln16][q * 8];
            #pragma unroll
            for (int c = 0; c < 2; ++c)
                bf2[c] = *(const v8bf*)&Bs[wid * 32 + c * 16 + ln16][q * 8];
            #pragma unroll
            for (int r = 0; r < 4; ++r)
                #pragma unroll
                for (int c = 0; c < 2; ++c)
                    sacc[r][c] = __builtin_amdgcn_mfma_f32_16x16x32_bf16(
                        af[r], bf2[c], sacc[r][c], 0, 0, 0);
            __syncthreads();
        }
        // ---- mask + C-layout -> Sl (A-operand layout source) ----
        bool maskt = (j == jmax);   // only overlap tile needs the mask
        #pragma unroll
        for (int r = 0; r < 4; ++r)
            #pragma unroll
            for (int c = 0; c < 2; ++c)
                #pragma unroll
                for (int e = 0; e < 4; ++e) {
                    int row = r * 16 + q * 4 + e;
                    int col = wid * 32 + c * 16 + ln16;
                    float v = sacc[r][c][e];
                    if (maskt && (iq * 64 + row) <= (j * 128 + col)) v = 0.f;
                    Sl[row][col] = f2b(v);
                }
        __syncthreads();
        // ---- P phase: Y[64x256] += S @ X_j over 128 k ----
        #pragma unroll
        for (int k0 = 0; k0 < 128; k0 += 32) {
            #pragma unroll
            for (int ci = 0; ci < 4; ++ci) {          // 16 chunks, 4/wave
                int c = wid * 4 + ci;
                int r = c * 16 + srl;
                g2l16(Xb + (long)r * T_ + j * 128 + k0 + scl,
                      (char*)Xs + c * 1024);
            }
            __syncthreads();
            v8bf pf[4], xf[4];
            #pragma unroll
            for (int m = 0; m < 4; ++m)
                pf[m] = *(const v8bf*)&Sl[m * 16 + ln16][k0 + q * 8];
            #pragma unroll
            for (int n = 0; n < 4; ++n)
                xf[n] = *(const v8bf*)&Xs[wid * 64 + n * 16 + ln16][q * 8];
            #pragma unroll
            for (int m = 0; m < 4; ++m)
                #pragma unroll
                for (int n = 0; n < 4; ++n)
                    yacc[m][n] = __builtin_amdgcn_mfma_f32_16x16x32_bf16(
                        pf[m], xf[n], yacc[m][n], 0, 0, 0);
            __syncthreads();
        }
    }
    // ---- epilogue: Y -> ykv bf16 ----
    #pragma unroll
    for (int m = 0; m < 4; ++m)
        #pragma unroll
        for (int n = 0; n < 4; ++n)
            #pragma unroll
            for (int e = 0; e < 4; ++e) {
                int t = iq * 64 + m * 16 + q * 4 + e;
                int d = dc * 256 + wid * 64 + n * 16 + ln16;
                ykv[((long)h * BT_ + (long)b * T_ + t) * D_ + d] =
                    f2b(yacc[m][n][e]);
            }
}

// ---------------------------------------------------------------------------
// Transpose + cast fp32 -> bf16: out[Cc][R] = (bf16) in[R][Cc], batched.
__global__ __launch_bounds__(256) void trans_cast(
    const float* __restrict__ in, long sIn, unsigned short* __restrict__ out,
    long sOut, int R, int Cc) {
    __shared__ float tl[32][33];
    int z = blockIdx.z;
    int r0 = blockIdx.y * 32, c0 = blockIdx.x * 32;
    int tx = threadIdx.x & 31, ty = threadIdx.x >> 5;
    const float* ip = in + (long)z * sIn;
    unsigned short* op = out + (long)z * sOut;
    #pragma unroll
    for (int j = 0; j < 4; ++j)
        tl[ty + j * 8][tx] = ip[(long)(r0 + ty + j * 8) * Cc + c0 + tx];
    __syncthreads();
    #pragma unroll
    for (int j = 0; j < 4; ++j)
        op[(long)(c0 + ty + j * 8) * R + r0 + tx] = f2b(tl[tx][ty + j * 8]);
}

// fp32 -> bf16 elementwise (n multiple of 1024)
__global__ __launch_bounds__(256) void cast_b(const float* __restrict__ in,
                                              unsigned short* __restrict__ out) {
    long i = ((long)blockIdx.x * 256 + threadIdx.x) * 4;
    float4 v = *(const float4*)&in[i];
    ushort4 o;
    o.x = f2b(v.x); o.y = f2b(v.y); o.z = f2b(v.z); o.w = f2b(v.w);
    *(ushort4*)&out[i] = o;
}

// out = t0+t1+t2+t3 + bias (4 split-K slices, rows of 512)
__global__ __launch_bounds__(256) void add_out4(const float* __restrict__ t,
                                                long slice,
                                                const float* __restrict__ bias,
                                                float* __restrict__ o) {
    long i = ((long)blockIdx.x * 256 + threadIdx.x) * 4;
    float4 v0 = *(const float4*)&t[i];
    float4 v1 = *(const float4*)&t[i + slice];
    float4 v2 = *(const float4*)&t[i + 2 * slice];
    float4 v3 = *(const float4*)&t[i + 3 * slice];
    float4 bv = *(const float4*)&bias[i & 511];
    float4 r;
    r.x = v0.x + v1.x + v2.x + v3.x + bv.x;
    r.y = v0.y + v1.y + v2.y + v3.y + bv.y;
    r.z = v0.z + v1.z + v2.z + v3.z + bv.z;
    r.w = v0.w + v1.w + v2.w + v3.w + bv.w;
    *(float4*)&o[i] = r;
}

// ---------------------------------------------------------------------------
// RoPE: xsp [BT][HN] bf16 -> qr [B][NH][T][NL] bf16 (head-outer layout).
__global__ __launch_bounds__(256) void rope_b(const unsigned short* __restrict__ xsp,
                                              unsigned short* __restrict__ qr) {
    long i = (long)blockIdx.x * 256 + threadIdx.x;  // group of 4 pairs
    int g = (int)(i & 255);
    long row = i >> 8;
    int h = g >> 5, n8 = g & 31;
    long b = row >> 11;
    int t = (int)(row & (T_ - 1));
    us8 u = *(const us8*)&xsp[row * HN_ + (long)g * 8];
    us8 o;
    #pragma unroll
    for (int p = 0; p < 4; ++p) {
        int n2 = n8 * 4 + p;
        float f = exp2f(-(float)n2 * 0.125f) * (float)(1.0 / (2.0 * M_PI));
        float ph = (float)t * f;
        ph = (ph - floorf(ph)) * (float)(2.0 * M_PI);
        float s, c;
        __sincosf(ph, &s, &c);
        float x0 = b2f(u[2 * p]), x1 = b2f(u[2 * p + 1]);
        o[2 * p]     = f2b(x0 * c - x1 * s);
        o[2 * p + 1] = f2b(x1 * c + x0 * s);
    }
    long ob = (((b * NH_ + h) * T_ + t) * NL_) + (long)n8 * 8;
    *(us8*)&qr[ob] = o;
}

// ---------------------------------------------------------------------------
// LayerNorm helpers (rows of 512, 256 threads, float2 per thread)
__device__ inline float2 block_reduce2(float a, float b) {
    __shared__ float sa[4], sb[4];
    #pragma unroll
    for (int off = 32; off; off >>= 1) {
        a += __shfl_down(a, off, 64);
        b += __shfl_down(b, off, 64);
    }
    __syncthreads();
    int w = threadIdx.x >> 6;
    if ((threadIdx.x & 63) == 0) { sa[w] = a; sb[w] = b; }
    __syncthreads();
    return make_float2(sa[0] + sa[1] + sa[2] + sa[3],
                       sb[0] + sb[1] + sb[2] + sb[3]);
}
__device__ inline float2 ln_pair(float2 v) {
    float2 s = block_reduce2(v.x + v.y, 0.f);
    float mu = s.x * (1.0f / 512.0f);
    float dx = v.x - mu, dy = v.y - mu;
    float2 q = block_reduce2(dx * dx + dy * dy, 0.f);
    float inv = rsqrtf(q.x * (1.0f / 512.0f) + 1e-5f);
    return make_float2(dx * inv, dy * inv);
}

// LN(sum of 4 slices + bias) -> fp32 + bf16
__global__ __launch_bounds__(256) void ln_dual4(const float* __restrict__ t,
                                                long slice,
                                                const float* __restrict__ bias,
                                                float* __restrict__ outf,
                                                unsigned short* __restrict__ outb) {
    long row = blockIdx.x;
    int c = threadIdx.x * 2;
    long i = row * 512 + c;
    float2 v0 = *(const float2*)&t[i];
    float2 v1 = *(const float2*)&t[i + slice];
    float2 v2 = *(const float2*)&t[i + 2 * slice];
    float2 v3 = *(const float2*)&t[i + 3 * slice];
    float2 bv = *(const float2*)&bias[c];
    float2 v = make_float2(v0.x + v1.x + v2.x + v3.x + bv.x,
                           v0.y + v1.y + v2.y + v3.y + bv.y);
    float2 o = ln_pair(v);
    *(float2*)&outf[i] = o;
    ushort2 ob; ob.x = f2b(o.x); ob.y = f2b(o.y);
    *(ushort2*)&outb[i] = ob;
}

// LN bf16 in-place
__global__ __launch_bounds__(256) void ln_b16(unsigned short* __restrict__ buf) {
    long row = blockIdx.x;
    ushort2 u = *(const ushort2*)&buf[row * 512 + threadIdx.x * 2];
    float2 v = make_float2(b2f(u.x), b2f(u.y));
    float2 o = ln_pair(v);
    ushort2 ob; ob.x = f2b(o.x); ob.y = f2b(o.y);
    *(ushort2*)&buf[row * 512 + threadIdx.x * 2] = ob;
}

// xs_next = LN(x_res + LN(sum of 4 ymlp slices)) -> fp32 + bf16
__global__ __launch_bounds__(256) void combine_dual4(
    const float* __restrict__ t, long slice, const float* __restrict__ xres,
    float* __restrict__ outf, unsigned short* __restrict__ outb) {
    long row = blockIdx.x;
    int c = threadIdx.x * 2;
    long i = row * 512 + c;
    float2 v0 = *(const float2*)&t[i];
    float2 v1 = *(const float2*)&t[i + slice];
    float2 v2 = *(const float2*)&t[i + 2 * slice];
    float2 v3 = *(const float2*)&t[i + 3 * slice];
    float2 y = make_float2(v0.x + v1.x + v2.x + v3.x,
                           v0.y + v1.y + v2.y + v3.y);
    float2 l = ln_pair(y);
    float2 r = *(const float2*)&xres[i];
    float2 z = make_float2(r.x + l.x, r.y + l.y);
    float2 o = ln_pair(z);
    *(float2*)&outf[i] = o;
    ushort2 ob; ob.x = f2b(o.x); ob.y = f2b(o.y);
    *(ushort2*)&outb[i] = ob;
}

// ---------------------------------------------------------------------------
extern "C" void kernel_launch(void* const* d_in, const int* in_sizes, int n_in,
                              void* d_out, int out_size, void* d_ws,
                              size_t ws_size, hipStream_t stream) {
    const float* x      = (const float*)d_in[0];
    const float* w_in   = (const float*)d_in[1];
    const float* b_in   = (const float*)d_in[2];
    const float* enc    = (const float*)d_in[3];
    const float* enc_v  = (const float*)d_in[4];
    const float* dec    = (const float*)d_in[5];
    const float* head_w = (const float*)d_in[6];
    const float* head_b = (const float*)d_in[7];
    float* out = (float*)d_out;

    // ---- workspace (~137 MB; Sp eliminated) ----
    char* w = (char*)d_ws;
    auto alloc = [&](size_t bytes) { void* p = (void*)w; w += bytes; return p; };
    unsigned short* w_inT = (unsigned short*)alloc((size_t)512 * 512 * 2);
    unsigned short* headT = (unsigned short*)alloc((size_t)512 * 512 * 2);
    unsigned short* encT  = (unsigned short*)alloc((size_t)NH_ * NL_ * D_ * 2);
    unsigned short* encvT = (unsigned short*)alloc((size_t)NH_ * NL_ * D_ * 2);
    unsigned short* decT  = (unsigned short*)alloc((size_t)D_ * HN_ * 2);
    unsigned short* xb    = (unsigned short*)alloc((size_t)BT_ * D_ * 2);
    float*          tmp   = (float*)alloc((size_t)4 * BT_ * D_ * 4);  // 4 K-slices
    float*          xsf0  = (float*)alloc((size_t)BT_ * D_ * 4);
    float*          xsf1  = (float*)alloc((size_t)BT_ * D_ * 4);
    unsigned short* xs_b  = (unsigned short*)alloc((size_t)BT_ * D_ * 2);
    unsigned short* xsT   = (unsigned short*)alloc((size_t)B_ * D_ * T_ * 2);
    unsigned short* xsp   = (unsigned short*)alloc((size_t)BT_ * HN_ * 2);
    unsigned short* qrh   = (unsigned short*)alloc((size_t)BT_ * HN_ * 2);
    unsigned short* ykv   = (unsigned short*)alloc((size_t)NH_ * BT_ * D_ * 2);
    const long SL = (long)BT_ * D_;   // split-K slice stride (elements)

    // ---- prep ----
    cast_b<<<BT_ * D_ / 1024, 256, 0, stream>>>(x, xb);
    trans_cast<<<dim3(16, 16, 1), 256, 0, stream>>>(w_in, 0, w_inT, 0, 512, 512);
    trans_cast<<<dim3(16, 16, 1), 256, 0, stream>>>(head_w, 0, headT, 0, 512, 512);
    trans_cast<<<dim3(8, 16, 8), 256, 0, stream>>>(enc, (long)D_ * NL_, encT,
                                                   (long)NL_ * D_, D_, NL_);
    trans_cast<<<dim3(8, 16, 8), 256, 0, stream>>>(enc_v, (long)D_ * NL_, encvT,
                                                   (long)NL_ * D_, D_, NL_);
    trans_cast<<<dim3(16, 64, 1), 256, 0, stream>>>(dec, 0, decT, 0, HN_, D_);

    // ---- xs = LN(x @ w_in + b_in)  (split-K=4, K=128/slice) ----
    gemm64<false, false, false>
        <<<dim3(4, 64, 4), 256, 0, stream>>>(xb, D_, 128, w_inT, D_, 128, tmp,
                                             D_, SL, nullptr, BT_, D_, 128);
    ln_dual4<<<BT_, 256, 0, stream>>>(tmp, SL, b_in, xsf0, xs_b);
    trans_cast<<<dim3(16, 64, 2), 256, 0, stream>>>(xsf0, (long)T_ * D_, xsT,
                                                    (long)D_ * T_, T_, D_);

    float* xin = xsf0;
    float* xout = xsf1;
    for (int l = 0; l < 3; ++l) {
        // x_sparse = relu(xs @ enc) -> bf16 [BT][HN]
        // (fusion across heads valid: A = xs is head-independent)
        gemm64<true, false, true>
            <<<dim3(16, 64, 1), 256, 0, stream>>>(
                xs_b, D_, 0, encT, D_, 0, xsp, HN_, 0, nullptr, BT_, HN_, D_);
        // QR = rope(x_sparse) -> [B][NH][T][NL]
        rope_b<<<BT_ * HN_ / 8 / 256, 256, 0, stream>>>(xsp, qrh);
        // yKV = strict_tril(QR QR^T) @ xs  — fused, S stays on-CU
        attn_fused<<<dim3(2, 32, 16), 256, 0, stream>>>(qrh, xsT, ykv);
        // yKV = LN(yKV) in place
        ln_b16<<<NH_ * BT_, 256, 0, stream>>>(ykv);
        // xy = relu(yKV[h] @ enc_v[h]) * x_sparse  — PER-HEAD batched
        gemm64<true, true, true>
            <<<dim3(2, 64, 8), 256, 0, stream>>>(
                ykv, D_, (long)BT_ * D_, encvT, D_, (long)NL_ * D_, xsp, HN_,
                NL_, xsp, BT_, NL_, D_);
        // yMLP = xy @ decoder  (split-K=4, K=512/slice) -> fp32 slices
        gemm64<false, false, false>
            <<<dim3(4, 64, 4), 256, 0, stream>>>(
                xsp, HN_, 512, decT, HN_, 512, tmp, D_, SL, nullptr, BT_, D_,
                512);
        // xs = LN(x_res + LN(yMLP))
        combine_dual4<<<BT_, 256, 0, stream>>>(tmp, SL, xin, xout, xs_b);
        trans_cast<<<dim3(16, 64, 2), 256, 0, stream>>>(xout, (long)T_ * D_,
                                                        xsT, (long)D_ * T_, T_,
                                                        D_);
        float* t = xin; xin = xout; xout = t;
    }

    // logits = xs @ head_w + head_b  (split-K=4)
    gemm64<false, false, false>
        <<<dim3(4, 64, 4), 256, 0, stream>>>(xs_b, D_, 128, headT, D_, 128, tmp,
                                             D_, SL, nullptr, BT_, D_, 128);
    add_out4<<<BT_ * 512 / 1024, 256, 0, stream>>>(tmp, SL, head_b, out);
}

// Round 8
// 909.530 us; speedup vs baseline: 1.4999x; 1.4999x over previous
//
#include <hip/hip_runtime.h>
#include <math.h>

constexpr int B_  = 2;
constexpr int T_  = 2048;
constexpr int D_  = 512;
constexpr int NH_ = 8;
constexpr int NL_ = 256;
constexpr int HN_ = NH_ * NL_;   // 2048
constexpr int BT_ = B_ * T_;     // 4096
constexpr int SLP = 136;         // padded Sl row (272 B = 17*16): free 2-way

typedef __bf16 v8bf __attribute__((ext_vector_type(8)));
typedef float  v4f  __attribute__((ext_vector_type(4)));
typedef unsigned short us8 __attribute__((ext_vector_type(8)));

__device__ inline unsigned short f2b(float f) {
    union { float f; unsigned u; } v{f};
    unsigned r = v.u + 0x7FFF + ((v.u >> 16) & 1);   // rtne
    return (unsigned short)(r >> 16);
}
__device__ inline float b2f(unsigned short u) {
    union { unsigned u; float f; } v{(unsigned)u << 16};
    return v.f;
}

// async 16B global->LDS (per-lane gaddr; LDS dest = wave-uniform base + lane*16)
__device__ __forceinline__ void g2l16(const void* g, void* l) {
    __builtin_amdgcn_global_load_lds(
        (const __attribute__((address_space(1))) void*)g,
        (__attribute__((address_space(3))) void*)l, 16, 0, 0);
}

// ===========================================================================
// 64x128-tile core ids (generic GEMM): 4 waves n-split 32, 4x2 MFMA.
#define T64_IDS                                               \
    int tid = threadIdx.x;                                    \
    int lane = tid & 63, wid = tid >> 6;                      \
    int wn = wid * 32;                                        \
    int ln16 = lane & 15, q = lane >> 4;                      \
    int srl = lane >> 2, scl = (lane & 3) * 8;

#define T64_STAGE(Ab, lda, Bb, ldb, k0)                       \
    _Pragma("unroll")                                         \
    for (int ci = 0; ci < 3; ++ci) {                          \
        int c = wid * 3 + ci;                                 \
        if (c < 4) {                                          \
            int r = c * 16 + srl;                             \
            g2l16(Ab + (long)r * lda + (k0) + scl, (char*)As + c * 1024); \
        } else {                                              \
            int r = (c - 4) * 16 + srl;                       \
            g2l16(Bb + (long)r * ldb + (k0) + scl, (char*)Bs + (c - 4) * 1024); \
        }                                                     \
    }

#define T64_MFMA(As, Bs)                                      \
    {                                                         \
        v8bf af[4], bf2[2];                                   \
        _Pragma("unroll")                                     \
        for (int r = 0; r < 4; ++r)                           \
            af[r] = *(const v8bf*)&As[r * 16 + ln16][q * 8];  \
        _Pragma("unroll")                                     \
        for (int c = 0; c < 2; ++c)                           \
            bf2[c] = *(const v8bf*)&Bs[wn + c * 16 + ln16][q * 8]; \
        _Pragma("unroll")                                     \
        for (int r = 0; r < 4; ++r)                           \
            _Pragma("unroll")                                 \
            for (int c = 0; c < 2; ++c)                       \
                acc[r][c] = __builtin_amdgcn_mfma_f32_16x16x32_bf16( \
                    af[r], bf2[c], acc[r][c], 0, 0, 0);       \
    }

// ---------------------------------------------------------------------------
// Generic 64-row bf16 GEMM: C[M,N] = A[M,K] @ Bt[N,K]^T, z-batched (split-K
// via sA/sB element offsets + sC output slices; per-head via matrix strides).
template <bool RELU, bool MUL, bool BF16OUT>
__global__ __launch_bounds__(256) void gemm64(
    const unsigned short* __restrict__ A, int lda, long sA,
    const unsigned short* __restrict__ Bt, int ldb, long sB,
    void* __restrict__ Cv, int ldc, long sC,
    const unsigned short* __restrict__ mulp, int M, int N, int K) {
    int m0 = blockIdx.y * 64, n0 = blockIdx.x * 128, z = blockIdx.z;
    __shared__ unsigned short As[64][32];    // 4 KB
    __shared__ unsigned short Bs[128][32];   // 8 KB
    const unsigned short* Ab = A  + (long)z * sA + (long)m0 * lda;
    const unsigned short* Bb = Bt + (long)z * sB + (long)n0 * ldb;
    T64_IDS
    v4f acc[4][2] = {};
    for (int k0 = 0; k0 < K; k0 += 32) {
        T64_STAGE(Ab, lda, Bb, ldb, k0)
        __syncthreads();
        T64_MFMA(As, Bs)
        __syncthreads();
    }
    float* Cf = (float*)Cv;
    unsigned short* Cb = (unsigned short*)Cv;
    long zoff = (long)z * sC;
    #pragma unroll
    for (int r = 0; r < 4; ++r)
        #pragma unroll
        for (int c = 0; c < 2; ++c)
            #pragma unroll
            for (int e = 0; e < 4; ++e) {
                int row = m0 + r * 16 + q * 4 + e;
                int col = n0 + wn + c * 16 + ln16;
                float v = acc[r][c][e];
                if (RELU) v = fmaxf(v, 0.f);
                long idx = zoff + (long)row * ldc + col;
                if (MUL) v *= b2f(mulp[idx]);
                if (BF16OUT) Cb[idx] = f2b(v);
                else         Cf[idx] = v;
            }
}

// ---------------------------------------------------------------------------
// Fused attention v2: yKV = strict_tril(QR QR^T) @ xs.  One block = 64-row
// Q-strip x FULL D=512; S computed ONCE per strip, never leaves the CU.
// grid (16 zz, 32 iq); zz->z swizzle pins each XCD to 2 same-batch heads
// (L%8 = zz%8), so QR (2x1 MB) + X (2 MB) stay L2-resident per XCD.
// Per j (<= iq/2): S(64x128) via MFMA (8 staged k-iters), mask overlap tile,
// C-layout -> Sl (A-layout source); P: 4 k-iters staging Xs[512][32] (all
// 4 D-chunks at once) -> 32 MFMA/wave/iter into yacc[4][8] (128 VGPR).
__global__ __launch_bounds__(256, 2) void attn_fused2(
    const unsigned short* __restrict__ qr,   // [B][NH][T][NL]
    const unsigned short* __restrict__ xsT,  // [B][D][T]
    unsigned short* __restrict__ ykv) {      // [NH][BT][D]
    __shared__ unsigned short As[64][32];    //  4 KB  QR_i k-chunk
    __shared__ unsigned short Bs[128][32];   //  8 KB  QR_j k-chunk
    __shared__ unsigned short Xs[512][32];   // 32 KB  X k-chunk, all D
    __shared__ unsigned short Sl[64][SLP];   // 17 KB  S strip (padded)
    int zz = blockIdx.x;
    int z = ((zz & 7) << 1) | (zz >> 3);     // XCD k <- heads {2k,2k+1} of one b
    int iq = 31 - blockIdx.y;                // heavy first
    int b = z >> 3, h = z & 7;
    const unsigned short* Qi = qr + ((long)z * T_ + iq * 64) * NL_;
    const unsigned short* Qz = qr + (long)z * T_ * NL_;
    const unsigned short* Xb = xsT + (long)b * D_ * T_;
    int tid = threadIdx.x;
    int lane = tid & 63, wid = tid >> 6;
    int ln16 = lane & 15, q = lane >> 4;
    int srl = lane >> 2, scl = (lane & 3) * 8;
    v4f yacc[4][8] = {};
    int jmax = iq >> 1;
    for (int j = 0; j <= jmax; ++j) {
        const unsigned short* Qj = Qz + (long)j * 128 * NL_;
        // ---- S phase: S[64x128] = QR_i @ QR_j^T over NL=256 ----
        v4f sacc[4][2] = {};
        for (int k8 = 0; k8 < 8; ++k8) {
            int kk = k8 * 32;
            #pragma unroll
            for (int ci = 0; ci < 3; ++ci) {          // 12 chunks, 3/wave
                int c = wid * 3 + ci;
                if (c < 4) {
                    int r = c * 16 + srl;
                    g2l16(Qi + (long)r * NL_ + kk + scl, (char*)As + c * 1024);
                } else {
                    int r = (c - 4) * 16 + srl;
                    g2l16(Qj + (long)r * NL_ + kk + scl,
                          (char*)Bs + (c - 4) * 1024);
                }
            }
            __syncthreads();
            v8bf af[4], bf2[2];
            #pragma unroll
            for (int r = 0; r < 4; ++r)
                af[r] = *(const v8bf*)&As[r * 16 + ln16][q * 8];
            #pragma unroll
            for (int c = 0; c < 2; ++c)
                bf2[c] = *(const v8bf*)&Bs[wid * 32 + c * 16 + ln16][q * 8];
            #pragma unroll
            for (int r = 0; r < 4; ++r)
                #pragma unroll
                for (int c = 0; c < 2; ++c)
                    sacc[r][c] = __builtin_amdgcn_mfma_f32_16x16x32_bf16(
                        af[r], bf2[c], sacc[r][c], 0, 0, 0);
            __syncthreads();
        }
        // ---- mask + C-layout -> Sl ----
        bool maskt = (j == jmax);   // only the overlap tile needs the mask
        #pragma unroll
        for (int r = 0; r < 4; ++r)
            #pragma unroll
            for (int c = 0; c < 2; ++c)
                #pragma unroll
                for (int e = 0; e < 4; ++e) {
                    int row = r * 16 + q * 4 + e;
                    int col = wid * 32 + c * 16 + ln16;
                    float v = sacc[r][c][e];
                    if (maskt && (iq * 64 + row) <= (j * 128 + col)) v = 0.f;
                    Sl[row][col] = f2b(v);
                }
        __syncthreads();
        // ---- P phase: Y[64x512] += S @ X_j, 4 k-iters of 32 ----
        #pragma unroll
        for (int k0 = 0; k0 < 128; k0 += 32) {
            #pragma unroll
            for (int i = 0; i < 8; ++i) {             // 32 chunks, 8/wave
                int c = wid * 8 + i;
                int dr = c * 16 + srl;                // d row 0..511
                g2l16(Xb + (long)dr * T_ + j * 128 + k0 + scl,
                      (char*)Xs + c * 1024);
            }
            __syncthreads();
            v8bf pf[4], xf[8];
            #pragma unroll
            for (int m = 0; m < 4; ++m)
                pf[m] = *(const v8bf*)&Sl[m * 16 + ln16][k0 + q * 8];
            #pragma unroll
            for (int n = 0; n < 8; ++n)
                xf[n] = *(const v8bf*)&Xs[wid * 128 + n * 16 + ln16][q * 8];
            #pragma unroll
            for (int m = 0; m < 4; ++m)
                #pragma unroll
                for (int n = 0; n < 8; ++n)
                    yacc[m][n] = __builtin_amdgcn_mfma_f32_16x16x32_bf16(
                        pf[m], xf[n], yacc[m][n], 0, 0, 0);
            __syncthreads();
        }
    }
    // ---- epilogue: Y -> ykv bf16 ----
    #pragma unroll
    for (int m = 0; m < 4; ++m)
        #pragma unroll
        for (int n = 0; n < 8; ++n)
            #pragma unroll
            for (int e = 0; e < 4; ++e) {
                int t = iq * 64 + m * 16 + q * 4 + e;
                int d = wid * 128 + n * 16 + ln16;
                ykv[((long)h * BT_ + (long)b * T_ + t) * D_ + d] =
                    f2b(yacc[m][n][e]);
            }
}

// ---------------------------------------------------------------------------
// Transpose + cast fp32 -> bf16: out[Cc][R] = (bf16) in[R][Cc], batched.
__global__ __launch_bounds__(256) void trans_cast(
    const float* __restrict__ in, long sIn, unsigned short* __restrict__ out,
    long sOut, int R, int Cc) {
    __shared__ float tl[32][33];
    int z = blockIdx.z;
    int r0 = blockIdx.y * 32, c0 = blockIdx.x * 32;
    int tx = threadIdx.x & 31, ty = threadIdx.x >> 5;
    const float* ip = in + (long)z * sIn;
    unsigned short* op = out + (long)z * sOut;
    #pragma unroll
    for (int j = 0; j < 4; ++j)
        tl[ty + j * 8][tx] = ip[(long)(r0 + ty + j * 8) * Cc + c0 + tx];
    __syncthreads();
    #pragma unroll
    for (int j = 0; j < 4; ++j)
        op[(long)(c0 + ty + j * 8) * R + r0 + tx] = f2b(tl[tx][ty + j * 8]);
}

// fp32 -> bf16 elementwise (n multiple of 1024)
__global__ __launch_bounds__(256) void cast_b(const float* __restrict__ in,
                                              unsigned short* __restrict__ out) {
    long i = ((long)blockIdx.x * 256 + threadIdx.x) * 4;
    float4 v = *(const float4*)&in[i];
    ushort4 o;
    o.x = f2b(v.x); o.y = f2b(v.y); o.z = f2b(v.z); o.w = f2b(v.w);
    *(ushort4*)&out[i] = o;
}

// out = t0+t1+t2+t3 + bias (4 split-K slices, rows of 512)
__global__ __launch_bounds__(256) void add_out4(const float* __restrict__ t,
                                                long slice,
                                                const float* __restrict__ bias,
                                                float* __restrict__ o) {
    long i = ((long)blockIdx.x * 256 + threadIdx.x) * 4;
    float4 v0 = *(const float4*)&t[i];
    float4 v1 = *(const float4*)&t[i + slice];
    float4 v2 = *(const float4*)&t[i + 2 * slice];
    float4 v3 = *(const float4*)&t[i + 3 * slice];
    float4 bv = *(const float4*)&bias[i & 511];
    float4 r;
    r.x = v0.x + v1.x + v2.x + v3.x + bv.x;
    r.y = v0.y + v1.y + v2.y + v3.y + bv.y;
    r.z = v0.z + v1.z + v2.z + v3.z + bv.z;
    r.w = v0.w + v1.w + v2.w + v3.w + bv.w;
    *(float4*)&o[i] = r;
}

// ---------------------------------------------------------------------------
// RoPE: xsp [BT][HN] bf16 -> qr [B][NH][T][NL] bf16 (head-outer layout).
__global__ __launch_bounds__(256) void rope_b(const unsigned short* __restrict__ xsp,
                                              unsigned short* __restrict__ qr) {
    long i = (long)blockIdx.x * 256 + threadIdx.x;  // group of 4 pairs
    int g = (int)(i & 255);
    long row = i >> 8;
    int h = g >> 5, n8 = g & 31;
    long b = row >> 11;
    int t = (int)(row & (T_ - 1));
    us8 u = *(const us8*)&xsp[row * HN_ + (long)g * 8];
    us8 o;
    #pragma unroll
    for (int p = 0; p < 4; ++p) {
        int n2 = n8 * 4 + p;
        float f = exp2f(-(float)n2 * 0.125f) * (float)(1.0 / (2.0 * M_PI));
        float ph = (float)t * f;
        ph = (ph - floorf(ph)) * (float)(2.0 * M_PI);
        float s, c;
        __sincosf(ph, &s, &c);
        float x0 = b2f(u[2 * p]), x1 = b2f(u[2 * p + 1]);
        o[2 * p]     = f2b(x0 * c - x1 * s);
        o[2 * p + 1] = f2b(x1 * c + x0 * s);
    }
    long ob = (((b * NH_ + h) * T_ + t) * NL_) + (long)n8 * 8;
    *(us8*)&qr[ob] = o;
}

// ---------------------------------------------------------------------------
// LayerNorm helpers (rows of 512, 256 threads, float2 per thread)
__device__ inline float2 block_reduce2(float a, float b) {
    __shared__ float sa[4], sb[4];
    #pragma unroll
    for (int off = 32; off; off >>= 1) {
        a += __shfl_down(a, off, 64);
        b += __shfl_down(b, off, 64);
    }
    __syncthreads();
    int w = threadIdx.x >> 6;
    if ((threadIdx.x & 63) == 0) { sa[w] = a; sb[w] = b; }
    __syncthreads();
    return make_float2(sa[0] + sa[1] + sa[2] + sa[3],
                       sb[0] + sb[1] + sb[2] + sb[3]);
}
__device__ inline float2 ln_pair(float2 v) {
    float2 s = block_reduce2(v.x + v.y, 0.f);
    float mu = s.x * (1.0f / 512.0f);
    float dx = v.x - mu, dy = v.y - mu;
    float2 q = block_reduce2(dx * dx + dy * dy, 0.f);
    float inv = rsqrtf(q.x * (1.0f / 512.0f) + 1e-5f);
    return make_float2(dx * inv, dy * inv);
}

// LN(sum of 4 slices + bias) -> fp32 + bf16
__global__ __launch_bounds__(256) void ln_dual4(const float* __restrict__ t,
                                                long slice,
                                                const float* __restrict__ bias,
                                                float* __restrict__ outf,
                                                unsigned short* __restrict__ outb) {
    long row = blockIdx.x;
    int c = threadIdx.x * 2;
    long i = row * 512 + c;
    float2 v0 = *(const float2*)&t[i];
    float2 v1 = *(const float2*)&t[i + slice];
    float2 v2 = *(const float2*)&t[i + 2 * slice];
    float2 v3 = *(const float2*)&t[i + 3 * slice];
    float2 bv = *(const float2*)&bias[c];
    float2 v = make_float2(v0.x + v1.x + v2.x + v3.x + bv.x,
                           v0.y + v1.y + v2.y + v3.y + bv.y);
    float2 o = ln_pair(v);
    *(float2*)&outf[i] = o;
    ushort2 ob; ob.x = f2b(o.x); ob.y = f2b(o.y);
    *(ushort2*)&outb[i] = ob;
}

// LN bf16 in-place
__global__ __launch_bounds__(256) void ln_b16(unsigned short* __restrict__ buf) {
    long row = blockIdx.x;
    ushort2 u = *(const ushort2*)&buf[row * 512 + threadIdx.x * 2];
    float2 v = make_float2(b2f(u.x), b2f(u.y));
    float2 o = ln_pair(v);
    ushort2 ob; ob.x = f2b(o.x); ob.y = f2b(o.y);
    *(ushort2*)&buf[row * 512 + threadIdx.x * 2] = ob;
}

// xs_next = LN(x_res + LN(sum of 4 ymlp slices)) -> fp32 + bf16
__global__ __launch_bounds__(256) void combine_dual4(
    const float* __restrict__ t, long slice, const float* __restrict__ xres,
    float* __restrict__ outf, unsigned short* __restrict__ outb) {
    long row = blockIdx.x;
    int c = threadIdx.x * 2;
    long i = row * 512 + c;
    float2 v0 = *(const float2*)&t[i];
    float2 v1 = *(const float2*)&t[i + slice];
    float2 v2 = *(const float2*)&t[i + 2 * slice];
    float2 v3 = *(const float2*)&t[i + 3 * slice];
    float2 y = make_float2(v0.x + v1.x + v2.x + v3.x,
                           v0.y + v1.y + v2.y + v3.y);
    float2 l = ln_pair(y);
    float2 r = *(const float2*)&xres[i];
    float2 z = make_float2(r.x + l.x, r.y + l.y);
    float2 o = ln_pair(z);
    *(float2*)&outf[i] = o;
    ushort2 ob; ob.x = f2b(o.x); ob.y = f2b(o.y);
    *(ushort2*)&outb[i] = ob;
}

// ---------------------------------------------------------------------------
extern "C" void kernel_launch(void* const* d_in, const int* in_sizes, int n_in,
                              void* d_out, int out_size, void* d_ws,
                              size_t ws_size, hipStream_t stream) {
    const float* x      = (const float*)d_in[0];
    const float* w_in   = (const float*)d_in[1];
    const float* b_in   = (const float*)d_in[2];
    const float* enc    = (const float*)d_in[3];
    const float* enc_v  = (const float*)d_in[4];
    const float* dec    = (const float*)d_in[5];
    const float* head_w = (const float*)d_in[6];
    const float* head_b = (const float*)d_in[7];
    float* out = (float*)d_out;

    // ---- workspace (~137 MB) ----
    char* w = (char*)d_ws;
    auto alloc = [&](size_t bytes) { void* p = (void*)w; w += bytes; return p; };
    unsigned short* w_inT = (unsigned short*)alloc((size_t)512 * 512 * 2);
    unsigned short* headT = (unsigned short*)alloc((size_t)512 * 512 * 2);
    unsigned short* encT  = (unsigned short*)alloc((size_t)NH_ * NL_ * D_ * 2);
    unsigned short* encvT = (unsigned short*)alloc((size_t)NH_ * NL_ * D_ * 2);
    unsigned short* decT  = (unsigned short*)alloc((size_t)D_ * HN_ * 2);
    unsigned short* xb    = (unsigned short*)alloc((size_t)BT_ * D_ * 2);
    float*          tmp   = (float*)alloc((size_t)4 * BT_ * D_ * 4);  // 4 K-slices
    float*          xsf0  = (float*)alloc((size_t)BT_ * D_ * 4);
    float*          xsf1  = (float*)alloc((size_t)BT_ * D_ * 4);
    unsigned short* xs_b  = (unsigned short*)alloc((size_t)BT_ * D_ * 2);
    unsigned short* xsT   = (unsigned short*)alloc((size_t)B_ * D_ * T_ * 2);
    unsigned short* xsp   = (unsigned short*)alloc((size_t)BT_ * HN_ * 2);
    unsigned short* qrh   = (unsigned short*)alloc((size_t)BT_ * HN_ * 2);
    unsigned short* ykv   = (unsigned short*)alloc((size_t)NH_ * BT_ * D_ * 2);
    const long SL = (long)BT_ * D_;   // split-K slice stride (elements)

    // ---- prep ----
    cast_b<<<BT_ * D_ / 1024, 256, 0, stream>>>(x, xb);
    trans_cast<<<dim3(16, 16, 1), 256, 0, stream>>>(w_in, 0, w_inT, 0, 512, 512);
    trans_cast<<<dim3(16, 16, 1), 256, 0, stream>>>(head_w, 0, headT, 0, 512, 512);
    trans_cast<<<dim3(8, 16, 8), 256, 0, stream>>>(enc, (long)D_ * NL_, encT,
                                                   (long)NL_ * D_, D_, NL_);
    trans_cast<<<dim3(8, 16, 8), 256, 0, stream>>>(enc_v, (long)D_ * NL_, encvT,
                                                   (long)NL_ * D_, D_, NL_);
    trans_cast<<<dim3(16, 64, 1), 256, 0, stream>>>(dec, 0, decT, 0, HN_, D_);

    // ---- xs = LN(x @ w_in + b_in)  (split-K=4, K=128/slice) ----
    gemm64<false, false, false>
        <<<dim3(4, 64, 4), 256, 0, stream>>>(xb, D_, 128, w_inT, D_, 128, tmp,
                                             D_, SL, nullptr, BT_, D_, 128);
    ln_dual4<<<BT_, 256, 0, stream>>>(tmp, SL, b_in, xsf0, xs_b);
    trans_cast<<<dim3(16, 64, 2), 256, 0, stream>>>(xsf0, (long)T_ * D_, xsT,
                                                    (long)D_ * T_, T_, D_);

    float* xin = xsf0;
    float* xout = xsf1;
    for (int l = 0; l < 3; ++l) {
        // x_sparse = relu(xs @ enc) -> bf16 [BT][HN]
        gemm64<true, false, true>
            <<<dim3(16, 64, 1), 256, 0, stream>>>(
                xs_b, D_, 0, encT, D_, 0, xsp, HN_, 0, nullptr, BT_, HN_, D_);
        // QR = rope(x_sparse) -> [B][NH][T][NL]
        rope_b<<<BT_ * HN_ / 8 / 256, 256, 0, stream>>>(xsp, qrh);
        // yKV = strict_tril(QR QR^T) @ xs — fused, S on-CU, full-D blocks
        attn_fused2<<<dim3(16, 32, 1), 256, 0, stream>>>(qrh, xsT, ykv);
        // yKV = LN(yKV) in place
        ln_b16<<<NH_ * BT_, 256, 0, stream>>>(ykv);
        // xy = relu(yKV[h] @ enc_v[h]) * x_sparse — per-head batched
        gemm64<true, true, true>
            <<<dim3(2, 64, 8), 256, 0, stream>>>(
                ykv, D_, (long)BT_ * D_, encvT, D_, (long)NL_ * D_, xsp, HN_,
                NL_, xsp, BT_, NL_, D_);
        // yMLP = xy @ decoder  (split-K=4, K=512/slice) -> fp32 slices
        gemm64<false, false, false>
            <<<dim3(4, 64, 4), 256, 0, stream>>>(
                xsp, HN_, 512, decT, HN_, 512, tmp, D_, SL, nullptr, BT_, D_,
                512);
        // xs = LN(x_res + LN(yMLP))
        combine_dual4<<<BT_, 256, 0, stream>>>(tmp, SL, xin, xout, xs_b);
        trans_cast<<<dim3(16, 64, 2), 256, 0, stream>>>(xout, (long)T_ * D_,
                                                        xsT, (long)D_ * T_, T_,
                                                        D_);
        float* t = xin; xin = xout; xout = t;
    }

    // logits = xs @ head_w + head_b  (split-K=4)
    gemm64<false, false, false>
        <<<dim3(4, 64, 4), 256, 0, stream>>>(xs_b, D_, 128, headT, D_, 128, tmp,
                                             D_, SL, nullptr, BT_, D_, 128);
    add_out4<<<BT_ * 512 / 1024, 256, 0, stream>>>(tmp, SL, head_b, out);
}

// Round 9
// 820.757 us; speedup vs baseline: 1.6621x; 1.1082x over previous
//
#include <hip/hip_runtime.h>
#include <math.h>

constexpr int B_  = 2;
constexpr int T_  = 2048;
constexpr int D_  = 512;
constexpr int NH_ = 8;
constexpr int NL_ = 256;
constexpr int HN_ = NH_ * NL_;   // 2048
constexpr int BT_ = B_ * T_;     // 4096
constexpr int NTIL = 16;         // T/128
constexpr int NTRI = NTIL * (NTIL + 1) / 2;      // 136 lower tiles
constexpr long STILE = (long)NTRI * 128 * 128;   // elems per (b,h) S slice

typedef __bf16 v8bf __attribute__((ext_vector_type(8)));
typedef float  v4f  __attribute__((ext_vector_type(4)));
typedef unsigned short us8 __attribute__((ext_vector_type(8)));

__device__ inline unsigned short f2b(float f) {
    union { float f; unsigned u; } v{f};
    unsigned r = v.u + 0x7FFF + ((v.u >> 16) & 1);   // rtne
    return (unsigned short)(r >> 16);
}
__device__ inline float b2f(unsigned short u) {
    union { unsigned u; float f; } v{(unsigned)u << 16};
    return v.f;
}

// async 16B global->LDS (per-lane gaddr; LDS dest = wave-uniform base + lane*16)
__device__ __forceinline__ void g2l16(const void* g, void* l) {
    __builtin_amdgcn_global_load_lds(
        (const __attribute__((address_space(1))) void*)g,
        (__attribute__((address_space(3))) void*)l, 16, 0, 0);
}

// ===========================================================================
// 128x128-tile core (s_gemm): 4 waves 2x2, 4x4 MFMA/wave.
#define TILE_IDS                                              \
    int tid = threadIdx.x;                                    \
    int lane = tid & 63, wid = tid >> 6;                      \
    int wm = (wid & 1) * 64, wn = (wid >> 1) * 64;            \
    int ln16 = lane & 15, q = lane >> 4;                      \
    int e0 = (wid * 2 + 0) * 512 + lane * 8;                  \
    int e1 = (wid * 2 + 1) * 512 + lane * 8;                  \
    int r0 = e0 >> 5, c0 = e0 & 31, r1 = e1 >> 5, c1 = e1 & 31;

#define TILE_MFMA(As, Bs)                                     \
    {                                                         \
        v8bf af[4], bfr[4];                                   \
        _Pragma("unroll")                                     \
        for (int r = 0; r < 4; ++r)                           \
            af[r] = *(const v8bf*)&As[wm + r * 16 + ln16][q * 8]; \
        _Pragma("unroll")                                     \
        for (int c = 0; c < 4; ++c)                           \
            bfr[c] = *(const v8bf*)&Bs[wn + c * 16 + ln16][q * 8]; \
        _Pragma("unroll")                                     \
        for (int r = 0; r < 4; ++r)                           \
            _Pragma("unroll")                                 \
            for (int c = 0; c < 4; ++c)                       \
                acc[r][c] = __builtin_amdgcn_mfma_f32_16x16x32_bf16( \
                    af[r], bfr[c], acc[r][c], 0, 0, 0);       \
    }

// ===========================================================================
// 64x128-tile core (generic GEMM): 4 waves n-split 32, 4x2 MFMA.
#define T64_IDS                                               \
    int tid = threadIdx.x;                                    \
    int lane = tid & 63, wid = tid >> 6;                      \
    int wn = wid * 32;                                        \
    int ln16 = lane & 15, q = lane >> 4;                      \
    int srl = lane >> 2, scl = (lane & 3) * 8;

#define T64_STAGE(Ab, lda, Bb, ldb, k0)                       \
    _Pragma("unroll")                                         \
    for (int ci = 0; ci < 3; ++ci) {                          \
        int c = wid * 3 + ci;                                 \
        if (c < 4) {                                          \
            int r = c * 16 + srl;                             \
            g2l16(Ab + (long)r * lda + (k0) + scl, (char*)As + c * 1024); \
        } else {                                              \
            int r = (c - 4) * 16 + srl;                       \
            g2l16(Bb + (long)r * ldb + (k0) + scl, (char*)Bs + (c - 4) * 1024); \
        }                                                     \
    }

#define T64_MFMA(As, Bs)                                      \
    {                                                         \
        v8bf af[4], bf2[2];                                   \
        _Pragma("unroll")                                     \
        for (int r = 0; r < 4; ++r)                           \
            af[r] = *(const v8bf*)&As[r * 16 + ln16][q * 8];  \
        _Pragma("unroll")                                     \
        for (int c = 0; c < 2; ++c)                           \
            bf2[c] = *(const v8bf*)&Bs[wn + c * 16 + ln16][q * 8]; \
        _Pragma("unroll")                                     \
        for (int r = 0; r < 4; ++r)                           \
            _Pragma("unroll")                                 \
            for (int c = 0; c < 2; ++c)                       \
                acc[r][c] = __builtin_amdgcn_mfma_f32_16x16x32_bf16( \
                    af[r], bf2[c], acc[r][c], 0, 0, 0);       \
    }

// ---------------------------------------------------------------------------
// Generic 64-row bf16 GEMM: C[M,N] = A[M,K] @ Bt[N,K]^T, z-batched (split-K
// via sA/sB element offsets + sC output slices; per-head via matrix strides).
template <bool RELU, bool MUL, bool BF16OUT>
__global__ __launch_bounds__(256) void gemm64(
    const unsigned short* __restrict__ A, int lda, long sA,
    const unsigned short* __restrict__ Bt, int ldb, long sB,
    void* __restrict__ Cv, int ldc, long sC,
    const unsigned short* __restrict__ mulp, int M, int N, int K) {
    int m0 = blockIdx.y * 64, n0 = blockIdx.x * 128, z = blockIdx.z;
    __shared__ unsigned short As[64][32];    // 4 KB
    __shared__ unsigned short Bs[128][32];   // 8 KB
    const unsigned short* Ab = A  + (long)z * sA + (long)m0 * lda;
    const unsigned short* Bb = Bt + (long)z * sB + (long)n0 * ldb;
    T64_IDS
    v4f acc[4][2] = {};
    for (int k0 = 0; k0 < K; k0 += 32) {
        T64_STAGE(Ab, lda, Bb, ldb, k0)
        __syncthreads();
        T64_MFMA(As, Bs)
        __syncthreads();
    }
    float* Cf = (float*)Cv;
    unsigned short* Cb = (unsigned short*)Cv;
    long zoff = (long)z * sC;
    #pragma unroll
    for (int r = 0; r < 4; ++r)
        #pragma unroll
        for (int c = 0; c < 2; ++c)
            #pragma unroll
            for (int e = 0; e < 4; ++e) {
                int row = m0 + r * 16 + q * 4 + e;
                int col = n0 + wn + c * 16 + ln16;
                float v = acc[r][c][e];
                if (RELU) v = fmaxf(v, 0.f);
                long idx = zoff + (long)row * ldc + col;
                if (MUL) v *= b2f(mulp[idx]);
                if (BF16OUT) Cb[idx] = f2b(v);
                else         Cf[idx] = v;
            }
}

// ---------------------------------------------------------------------------
// S-GEMM: packed-triangular scores (128-tile).  grid (16 z, NTRI);
// z in blockIdx.x so L%8 = z%8 pins each z's QR slice (1 MB) to one XCD.
__global__ __launch_bounds__(256) void s_gemm(const unsigned short* __restrict__ qr,
                                              unsigned short* __restrict__ Sp) {
    int x = blockIdx.y, z = blockIdx.x;
    int i = 0, rem = x;
    while (rem >= i + 1) { rem -= i + 1; ++i; }
    int j = rem;                       // tile (i, j), j <= i
    const unsigned short* zb = qr + (long)z * T_ * NL_;
    const unsigned short* Ab = zb + (long)(i * 128) * NL_;
    const unsigned short* Bb = zb + (long)(j * 128) * NL_;
    __shared__ unsigned short As[128][32];
    __shared__ unsigned short Bs[128][32];
    TILE_IDS
    v4f acc[4][4] = {};
    for (int k0 = 0; k0 < NL_; k0 += 32) {
        g2l16(Ab + (long)r0 * NL_ + k0 + c0, (char*)As + (wid * 2 + 0) * 1024);
        g2l16(Ab + (long)r1 * NL_ + k0 + c1, (char*)As + (wid * 2 + 1) * 1024);
        g2l16(Bb + (long)r0 * NL_ + k0 + c0, (char*)Bs + (wid * 2 + 0) * 1024);
        g2l16(Bb + (long)r1 * NL_ + k0 + c1, (char*)Bs + (wid * 2 + 1) * 1024);
        __syncthreads();
        TILE_MFMA(As, Bs)
        __syncthreads();
    }
    unsigned short* ob = Sp + (long)z * STILE + (long)x * 16384;
    bool diag = (i == j);
    #pragma unroll
    for (int r = 0; r < 4; ++r)
        #pragma unroll
        for (int c = 0; c < 4; ++c)
            #pragma unroll
            for (int e = 0; e < 4; ++e) {
                int row = wm + r * 16 + q * 4 + e;
                int col = wn + c * 16 + ln16;
                float v = acc[r][c][e];
                if (diag && row <= col) v = 0.f;   // strict causal
                ob[row * 128 + col] = f2b(v);
            }
}

// ---------------------------------------------------------------------------
// PX512: yKV = S @ xs, packed-tri A, 64-row strip x FULL D=512 per block.
// grid (16 z, 32 my): z fastest -> XCD pin; my = 31-by heavy-first.
// Each S tile is read by exactly ONE block (no S re-read).  Per k-round:
// stage As 4KB (1 chunk/wave) + Xs[512][32] 32KB (8 chunks/wave), then
// 32 MFMA/wave into yacc[4][8] (128 VGPR).  LDS 36 KB.
__global__ __launch_bounds__(256) void px512(const unsigned short* __restrict__ Sp,
                                             const unsigned short* __restrict__ xsT,
                                             unsigned short* __restrict__ ykv) {
    int z = blockIdx.x;
    int my = 31 - blockIdx.y;          // 64-row strip, heavy first
    int b = z >> 3, h = z & 7;
    int ti = my >> 1;                  // 128-tile row
    const unsigned short* Ab = Sp + (long)z * STILE +
                               (long)(ti * (ti + 1) / 2) * 16384 +
                               (long)(my & 1) * 64 * 128;
    const unsigned short* Xb = xsT + (long)b * D_ * T_;
    __shared__ unsigned short As[64][32];    //  4 KB
    __shared__ unsigned short Xs[512][32];   // 32 KB
    int tid = threadIdx.x;
    int lane = tid & 63, wid = tid >> 6;
    int ln16 = lane & 15, q = lane >> 4;
    int srl = lane >> 2, scl = (lane & 3) * 8;
    v4f yacc[4][8] = {};
    int kend = (ti + 1) * 128;
    for (int k0 = 0; k0 < kend; k0 += 32) {
        const unsigned short* At = Ab + ((long)(k0 >> 7) << 14);
        int kc = k0 & 127;
        // A: 4 chunks, one per wave
        g2l16(At + (wid * 16 + srl) * 128 + kc + scl, (char*)As + wid * 1024);
        // X: 32 chunks, 8 per wave
        #pragma unroll
        for (int i = 0; i < 8; ++i) {
            int c = wid * 8 + i;
            int dr = c * 16 + srl;
            g2l16(Xb + (long)dr * T_ + k0 + scl, (char*)Xs + c * 1024);
        }
        __syncthreads();
        v8bf af[4], xf[8];
        #pragma unroll
        for (int m = 0; m < 4; ++m)
            af[m] = *(const v8bf*)&As[m * 16 + ln16][q * 8];
        #pragma unroll
        for (int n = 0; n < 8; ++n)
            xf[n] = *(const v8bf*)&Xs[wid * 128 + n * 16 + ln16][q * 8];
        #pragma unroll
        for (int m = 0; m < 4; ++m)
            #pragma unroll
            for (int n = 0; n < 8; ++n)
                yacc[m][n] = __builtin_amdgcn_mfma_f32_16x16x32_bf16(
                    af[m], xf[n], yacc[m][n], 0, 0, 0);
        __syncthreads();
    }
    #pragma unroll
    for (int m = 0; m < 4; ++m)
        #pragma unroll
        for (int n = 0; n < 8; ++n)
            #pragma unroll
            for (int e = 0; e < 4; ++e) {
                int t = my * 64 + m * 16 + q * 4 + e;
                int d = wid * 128 + n * 16 + ln16;
                ykv[((long)h * BT_ + (long)b * T_ + t) * D_ + d] =
                    f2b(yacc[m][n][e]);
            }
}

// ---------------------------------------------------------------------------
// Transpose + cast fp32 -> bf16: out[Cc][R] = (bf16) in[R][Cc], batched.
__global__ __launch_bounds__(256) void trans_cast(
    const float* __restrict__ in, long sIn, unsigned short* __restrict__ out,
    long sOut, int R, int Cc) {
    __shared__ float tl[32][33];
    int z = blockIdx.z;
    int r0 = blockIdx.y * 32, c0 = blockIdx.x * 32;
    int tx = threadIdx.x & 31, ty = threadIdx.x >> 5;
    const float* ip = in + (long)z * sIn;
    unsigned short* op = out + (long)z * sOut;
    #pragma unroll
    for (int j = 0; j < 4; ++j)
        tl[ty + j * 8][tx] = ip[(long)(r0 + ty + j * 8) * Cc + c0 + tx];
    __syncthreads();
    #pragma unroll
    for (int j = 0; j < 4; ++j)
        op[(long)(c0 + ty + j * 8) * R + r0 + tx] = f2b(tl[tx][ty + j * 8]);
}

// fp32 -> bf16 elementwise (n multiple of 1024)
__global__ __launch_bounds__(256) void cast_b(const float* __restrict__ in,
                                              unsigned short* __restrict__ out) {
    long i = ((long)blockIdx.x * 256 + threadIdx.x) * 4;
    float4 v = *(const float4*)&in[i];
    ushort4 o;
    o.x = f2b(v.x); o.y = f2b(v.y); o.z = f2b(v.z); o.w = f2b(v.w);
    *(ushort4*)&out[i] = o;
}

// out = t0+t1+t2+t3 + bias (4 split-K slices, rows of 512)
__global__ __launch_bounds__(256) void add_out4(const float* __restrict__ t,
                                                long slice,
                                                const float* __restrict__ bias,
                                                float* __restrict__ o) {
    long i = ((long)blockIdx.x * 256 + threadIdx.x) * 4;
    float4 v0 = *(const float4*)&t[i];
    float4 v1 = *(const float4*)&t[i + slice];
    float4 v2 = *(const float4*)&t[i + 2 * slice];
    float4 v3 = *(const float4*)&t[i + 3 * slice];
    float4 bv = *(const float4*)&bias[i & 511];
    float4 r;
    r.x = v0.x + v1.x + v2.x + v3.x + bv.x;
    r.y = v0.y + v1.y + v2.y + v3.y + bv.y;
    r.z = v0.z + v1.z + v2.z + v3.z + bv.z;
    r.w = v0.w + v1.w + v2.w + v3.w + bv.w;
    *(float4*)&o[i] = r;
}

// ---------------------------------------------------------------------------
// RoPE: xsp [BT][HN] bf16 -> qr [B][NH][T][NL] bf16 (head-outer layout).
__global__ __launch_bounds__(256) void rope_b(const unsigned short* __restrict__ xsp,
                                              unsigned short* __restrict__ qr) {
    long i = (long)blockIdx.x * 256 + threadIdx.x;  // group of 4 pairs
    int g = (int)(i & 255);
    long row = i >> 8;
    int h = g >> 5, n8 = g & 31;
    long b = row >> 11;
    int t = (int)(row & (T_ - 1));
    us8 u = *(const us8*)&xsp[row * HN_ + (long)g * 8];
    us8 o;
    #pragma unroll
    for (int p = 0; p < 4; ++p) {
        int n2 = n8 * 4 + p;
        float f = exp2f(-(float)n2 * 0.125f) * (float)(1.0 / (2.0 * M_PI));
        float ph = (float)t * f;
        ph = (ph - floorf(ph)) * (float)(2.0 * M_PI);
        float s, c;
        __sincosf(ph, &s, &c);
        float x0 = b2f(u[2 * p]), x1 = b2f(u[2 * p + 1]);
        o[2 * p]     = f2b(x0 * c - x1 * s);
        o[2 * p + 1] = f2b(x1 * c + x0 * s);
    }
    long ob = (((b * NH_ + h) * T_ + t) * NL_) + (long)n8 * 8;
    *(us8*)&qr[ob] = o;
}

// ---------------------------------------------------------------------------
// LayerNorm helpers (rows of 512, 256 threads, float2 per thread)
__device__ inline float2 block_reduce2(float a, float b) {
    __shared__ float sa[4], sb[4];
    #pragma unroll
    for (int off = 32; off; off >>= 1) {
        a += __shfl_down(a, off, 64);
        b += __shfl_down(b, off, 64);
    }
    __syncthreads();
    int w = threadIdx.x >> 6;
    if ((threadIdx.x & 63) == 0) { sa[w] = a; sb[w] = b; }
    __syncthreads();
    return make_float2(sa[0] + sa[1] + sa[2] + sa[3],
                       sb[0] + sb[1] + sb[2] + sb[3]);
}
__device__ inline float2 ln_pair(float2 v) {
    float2 s = block_reduce2(v.x + v.y, 0.f);
    float mu = s.x * (1.0f / 512.0f);
    float dx = v.x - mu, dy = v.y - mu;
    float2 q = block_reduce2(dx * dx + dy * dy, 0.f);
    float inv = rsqrtf(q.x * (1.0f / 512.0f) + 1e-5f);
    return make_float2(dx * inv, dy * inv);
}

// LN(sum of 4 slices + bias) -> fp32 + bf16
__global__ __launch_bounds__(256) void ln_dual4(const float* __restrict__ t,
                                                long slice,
                                                const float* __restrict__ bias,
                                                float* __restrict__ outf,
                                                unsigned short* __restrict__ outb) {
    long row = blockIdx.x;
    int c = threadIdx.x * 2;
    long i = row * 512 + c;
    float2 v0 = *(const float2*)&t[i];
    float2 v1 = *(const float2*)&t[i + slice];
    float2 v2 = *(const float2*)&t[i + 2 * slice];
    float2 v3 = *(const float2*)&t[i + 3 * slice];
    float2 bv = *(const float2*)&bias[c];
    float2 v = make_float2(v0.x + v1.x + v2.x + v3.x + bv.x,
                           v0.y + v1.y + v2.y + v3.y + bv.y);
    float2 o = ln_pair(v);
    *(float2*)&outf[i] = o;
    ushort2 ob; ob.x = f2b(o.x); ob.y = f2b(o.y);
    *(ushort2*)&outb[i] = ob;
}

// LN bf16 in-place
__global__ __launch_bounds__(256) void ln_b16(unsigned short* __restrict__ buf) {
    long row = blockIdx.x;
    ushort2 u = *(const ushort2*)&buf[row * 512 + threadIdx.x * 2];
    float2 v = make_float2(b2f(u.x), b2f(u.y));
    float2 o = ln_pair(v);
    ushort2 ob; ob.x = f2b(o.x); ob.y = f2b(o.y);
    *(ushort2*)&buf[row * 512 + threadIdx.x * 2] = ob;
}

// xs_next = LN(x_res + LN(sum of 4 ymlp slices)) -> fp32 + bf16
__global__ __launch_bounds__(256) void combine_dual4(
    const float* __restrict__ t, long slice, const float* __restrict__ xres,
    float* __restrict__ outf, unsigned short* __restrict__ outb) {
    long row = blockIdx.x;
    int c = threadIdx.x * 2;
    long i = row * 512 + c;
    float2 v0 = *(const float2*)&t[i];
    float2 v1 = *(const float2*)&t[i + slice];
    float2 v2 = *(const float2*)&t[i + 2 * slice];
    float2 v3 = *(const float2*)&t[i + 3 * slice];
    float2 y = make_float2(v0.x + v1.x + v2.x + v3.x,
                           v0.y + v1.y + v2.y + v3.y);
    float2 l = ln_pair(y);
    float2 r = *(const float2*)&xres[i];
    float2 z = make_float2(r.x + l.x, r.y + l.y);
    float2 o = ln_pair(z);
    *(float2*)&outf[i] = o;
    ushort2 ob; ob.x = f2b(o.x); ob.y = f2b(o.y);
    *(ushort2*)&outb[i] = ob;
}

// ---------------------------------------------------------------------------
extern "C" void kernel_launch(void* const* d_in, const int* in_sizes, int n_in,
                              void* d_out, int out_size, void* d_ws,
                              size_t ws_size, hipStream_t stream) {
    const float* x      = (const float*)d_in[0];
    const float* w_in   = (const float*)d_in[1];
    const float* b_in   = (const float*)d_in[2];
    const float* enc    = (const float*)d_in[3];
    const float* enc_v  = (const float*)d_in[4];
    const float* dec    = (const float*)d_in[5];
    const float* head_w = (const float*)d_in[6];
    const float* head_b = (const float*)d_in[7];
    float* out = (float*)d_out;

    // ---- workspace (~209 MB) ----
    char* w = (char*)d_ws;
    auto alloc = [&](size_t bytes) { void* p = (void*)w; w += bytes; return p; };
    unsigned short* w_inT = (unsigned short*)alloc((size_t)512 * 512 * 2);
    unsigned short* headT = (unsigned short*)alloc((size_t)512 * 512 * 2);
    unsigned short* encT  = (unsigned short*)alloc((size_t)NH_ * NL_ * D_ * 2);
    unsigned short* encvT = (unsigned short*)alloc((size_t)NH_ * NL_ * D_ * 2);
    unsigned short* decT  = (unsigned short*)alloc((size_t)D_ * HN_ * 2);
    unsigned short* xb    = (unsigned short*)alloc((size_t)BT_ * D_ * 2);
    float*          tmp   = (float*)alloc((size_t)4 * BT_ * D_ * 4);  // 4 K-slices
    float*          xsf0  = (float*)alloc((size_t)BT_ * D_ * 4);
    float*          xsf1  = (float*)alloc((size_t)BT_ * D_ * 4);
    unsigned short* xs_b  = (unsigned short*)alloc((size_t)BT_ * D_ * 2);
    unsigned short* xsT   = (unsigned short*)alloc((size_t)B_ * D_ * T_ * 2);
    unsigned short* xsp   = (unsigned short*)alloc((size_t)BT_ * HN_ * 2);
    unsigned short* qrh   = (unsigned short*)alloc((size_t)BT_ * HN_ * 2);
    unsigned short* Sp    = (unsigned short*)alloc((size_t)16 * STILE * 2);
    unsigned short* ykv   = (unsigned short*)alloc((size_t)NH_ * BT_ * D_ * 2);
    const long SL = (long)BT_ * D_;   // split-K slice stride (elements)

    // ---- prep ----
    cast_b<<<BT_ * D_ / 1024, 256, 0, stream>>>(x, xb);
    trans_cast<<<dim3(16, 16, 1), 256, 0, stream>>>(w_in, 0, w_inT, 0, 512, 512);
    trans_cast<<<dim3(16, 16, 1), 256, 0, stream>>>(head_w, 0, headT, 0, 512, 512);
    trans_cast<<<dim3(8, 16, 8), 256, 0, stream>>>(enc, (long)D_ * NL_, encT,
                                                   (long)NL_ * D_, D_, NL_);
    trans_cast<<<dim3(8, 16, 8), 256, 0, stream>>>(enc_v, (long)D_ * NL_, encvT,
                                                   (long)NL_ * D_, D_, NL_);
    trans_cast<<<dim3(16, 64, 1), 256, 0, stream>>>(dec, 0, decT, 0, HN_, D_);

    // ---- xs = LN(x @ w_in + b_in)  (split-K=4, K=128/slice) ----
    gemm64<false, false, false>
        <<<dim3(4, 64, 4), 256, 0, stream>>>(xb, D_, 128, w_inT, D_, 128, tmp,
                                             D_, SL, nullptr, BT_, D_, 128);
    ln_dual4<<<BT_, 256, 0, stream>>>(tmp, SL, b_in, xsf0, xs_b);
    trans_cast<<<dim3(16, 64, 2), 256, 0, stream>>>(xsf0, (long)T_ * D_, xsT,
                                                    (long)D_ * T_, T_, D_);

    float* xin = xsf0;
    float* xout = xsf1;
    for (int l = 0; l < 3; ++l) {
        // x_sparse = relu(xs @ enc) -> bf16 [BT][HN]
        gemm64<true, false, true>
            <<<dim3(16, 64, 1), 256, 0, stream>>>(
                xs_b, D_, 0, encT, D_, 0, xsp, HN_, 0, nullptr, BT_, HN_, D_);
        // QR = rope(x_sparse) -> [B][NH][T][NL]
        rope_b<<<BT_ * HN_ / 8 / 256, 256, 0, stream>>>(xsp, qrh);
        // S = strict_tril(QR QR^T), packed tiles, z XCD-pinned
        s_gemm<<<dim3(16, NTRI), 256, 0, stream>>>(qrh, Sp);
        // yKV = S @ xs, full-D strips, each S tile read once, heavy-first
        px512<<<dim3(16, 32), 256, 0, stream>>>(Sp, xsT, ykv);
        // yKV = LN(yKV) in place
        ln_b16<<<NH_ * BT_, 256, 0, stream>>>(ykv);
        // xy = relu(yKV[h] @ enc_v[h]) * x_sparse — per-head batched
        gemm64<true, true, true>
            <<<dim3(2, 64, 8), 256, 0, stream>>>(
                ykv, D_, (long)BT_ * D_, encvT, D_, (long)NL_ * D_, xsp, HN_,
                NL_, xsp, BT_, NL_, D_);
        // yMLP = xy @ decoder  (split-K=4, K=512/slice) -> fp32 slices
        gemm64<false, false, false>
            <<<dim3(4, 64, 4), 256, 0, stream>>>(
                xsp, HN_, 512, decT, HN_, 512, tmp, D_, SL, nullptr, BT_, D_,
                512);
        // xs = LN(x_res + LN(yMLP))
        combine_dual4<<<BT_, 256, 0, stream>>>(tmp, SL, xin, xout, xs_b);
        trans_cast<<<dim3(16, 64, 2), 256, 0, stream>>>(xout, (long)T_ * D_,
                                                        xsT, (long)D_ * T_, T_,
                                                        D_);
        float* t = xin; xin = xout; xout = t;
    }

    // logits = xs @ head_w + head_b  (split-K=4)
    gemm64<false, false, false>
        <<<dim3(4, 64, 4), 256, 0, stream>>>(xs_b, D_, 128, headT, D_, 128, tmp,
                                             D_, SL, nullptr, BT_, D_, 128);
    add_out4<<<BT_ * 512 / 1024, 256, 0, stream>>>(tmp, SL, head_b, out);
}

// Round 10
// 763.911 us; speedup vs baseline: 1.7858x; 1.0744x over previous
//
#include <hip/hip_runtime.h>
#include <math.h>

constexpr int B_  = 2;
constexpr int T_  = 2048;
constexpr int D_  = 512;
constexpr int NH_ = 8;
constexpr int NL_ = 256;
constexpr int HN_ = NH_ * NL_;   // 2048
constexpr int BT_ = B_ * T_;     // 4096
constexpr int NTIL = 16;         // T/128
constexpr int NTRI = NTIL * (NTIL + 1) / 2;      // 136 lower tiles
constexpr long STILE = (long)NTRI * 128 * 128;   // elems per (b,h) S slice

typedef __bf16 v8bf __attribute__((ext_vector_type(8)));
typedef float  v4f  __attribute__((ext_vector_type(4)));
typedef unsigned short us8 __attribute__((ext_vector_type(8)));

__device__ inline unsigned short f2b(float f) {
    union { float f; unsigned u; } v{f};
    unsigned r = v.u + 0x7FFF + ((v.u >> 16) & 1);   // rtne
    return (unsigned short)(r >> 16);
}
__device__ inline float b2f(unsigned short u) {
    union { unsigned u; float f; } v{(unsigned)u << 16};
    return v.f;
}

// async 16B global->LDS (per-lane gaddr; LDS dest = wave-uniform base + lane*16)
__device__ __forceinline__ void g2l16(const void* g, void* l) {
    __builtin_amdgcn_global_load_lds(
        (const __attribute__((address_space(1))) void*)g,
        (__attribute__((address_space(3))) void*)l, 16, 0, 0);
}

// ===========================================================================
// 128x128-tile core (s_gemm): 4 waves 2x2, 4x4 MFMA/wave.
#define TILE_IDS                                              \
    int tid = threadIdx.x;                                    \
    int lane = tid & 63, wid = tid >> 6;                      \
    int wm = (wid & 1) * 64, wn = (wid >> 1) * 64;            \
    int ln16 = lane & 15, q = lane >> 4;                      \
    int e0 = (wid * 2 + 0) * 512 + lane * 8;                  \
    int e1 = (wid * 2 + 1) * 512 + lane * 8;                  \
    int r0 = e0 >> 5, c0 = e0 & 31, r1 = e1 >> 5, c1 = e1 & 31;

#define TILE_MFMA(As, Bs)                                     \
    {                                                         \
        v8bf af[4], bfr[4];                                   \
        _Pragma("unroll")                                     \
        for (int r = 0; r < 4; ++r)                           \
            af[r] = *(const v8bf*)&As[wm + r * 16 + ln16][q * 8]; \
        _Pragma("unroll")                                     \
        for (int c = 0; c < 4; ++c)                           \
            bfr[c] = *(const v8bf*)&Bs[wn + c * 16 + ln16][q * 8]; \
        _Pragma("unroll")                                     \
        for (int r = 0; r < 4; ++r)                           \
            _Pragma("unroll")                                 \
            for (int c = 0; c < 4; ++c)                       \
                acc[r][c] = __builtin_amdgcn_mfma_f32_16x16x32_bf16( \
                    af[r], bfr[c], acc[r][c], 0, 0, 0);       \
    }

// ===========================================================================
// 64x128-tile core (generic GEMM): 4 waves n-split 32, 4x2 MFMA.
#define T64_IDS                                               \
    int tid = threadIdx.x;                                    \
    int lane = tid & 63, wid = tid >> 6;                      \
    int wn = wid * 32;                                        \
    int ln16 = lane & 15, q = lane >> 4;                      \
    int srl = lane >> 2, scl = (lane & 3) * 8;

#define T64_STAGE(Ab, lda, Bb, ldb, k0)                       \
    _Pragma("unroll")                                         \
    for (int ci = 0; ci < 3; ++ci) {                          \
        int c = wid * 3 + ci;                                 \
        if (c < 4) {                                          \
            int r = c * 16 + srl;                             \
            g2l16(Ab + (long)r * lda + (k0) + scl, (char*)As + c * 1024); \
        } else {                                              \
            int r = (c - 4) * 16 + srl;                       \
            g2l16(Bb + (long)r * ldb + (k0) + scl, (char*)Bs + (c - 4) * 1024); \
        }                                                     \
    }

#define T64_MFMA(As, Bs)                                      \
    {                                                         \
        v8bf af[4], bf2[2];                                   \
        _Pragma("unroll")                                     \
        for (int r = 0; r < 4; ++r)                           \
            af[r] = *(const v8bf*)&As[r * 16 + ln16][q * 8];  \
        _Pragma("unroll")                                     \
        for (int c = 0; c < 2; ++c)                           \
            bf2[c] = *(const v8bf*)&Bs[wn + c * 16 + ln16][q * 8]; \
        _Pragma("unroll")                                     \
        for (int r = 0; r < 4; ++r)                           \
            _Pragma("unroll")                                 \
            for (int c = 0; c < 2; ++c)                       \
                acc[r][c] = __builtin_amdgcn_mfma_f32_16x16x32_bf16( \
                    af[r], bf2[c], acc[r][c], 0, 0, 0);       \
    }

// ---------------------------------------------------------------------------
// Generic 64-row bf16 GEMM: C[M,N] = A[M,K] @ Bt[N,K]^T, z-batched (split-K
// via sA/sB element offsets + sC output slices; per-head via matrix strides).
template <bool RELU, bool MUL, bool BF16OUT>
__global__ __launch_bounds__(256) void gemm64(
    const unsigned short* __restrict__ A, int lda, long sA,
    const unsigned short* __restrict__ Bt, int ldb, long sB,
    void* __restrict__ Cv, int ldc, long sC,
    const unsigned short* __restrict__ mulp, int M, int N, int K) {
    int m0 = blockIdx.y * 64, n0 = blockIdx.x * 128, z = blockIdx.z;
    __shared__ unsigned short As[64][32];    // 4 KB
    __shared__ unsigned short Bs[128][32];   // 8 KB
    const unsigned short* Ab = A  + (long)z * sA + (long)m0 * lda;
    const unsigned short* Bb = Bt + (long)z * sB + (long)n0 * ldb;
    T64_IDS
    v4f acc[4][2] = {};
    for (int k0 = 0; k0 < K; k0 += 32) {
        T64_STAGE(Ab, lda, Bb, ldb, k0)
        __syncthreads();
        T64_MFMA(As, Bs)
        __syncthreads();
    }
    float* Cf = (float*)Cv;
    unsigned short* Cb = (unsigned short*)Cv;
    long zoff = (long)z * sC;
    #pragma unroll
    for (int r = 0; r < 4; ++r)
        #pragma unroll
        for (int c = 0; c < 2; ++c)
            #pragma unroll
            for (int e = 0; e < 4; ++e) {
                int row = m0 + r * 16 + q * 4 + e;
                int col = n0 + wn + c * 16 + ln16;
                float v = acc[r][c][e];
                if (RELU) v = fmaxf(v, 0.f);
                long idx = zoff + (long)row * ldc + col;
                if (MUL) v *= b2f(mulp[idx]);
                if (BF16OUT) Cb[idx] = f2b(v);
                else         Cf[idx] = v;
            }
}

// ---------------------------------------------------------------------------
// S-GEMM: packed-triangular scores (128-tile).  grid (16 z, NTRI);
// z in blockIdx.x so L%8 = z%8 pins each z's QR slice (1 MB) to one XCD.
__global__ __launch_bounds__(256) void s_gemm(const unsigned short* __restrict__ qr,
                                              unsigned short* __restrict__ Sp) {
    int x = blockIdx.y, z = blockIdx.x;
    int i = 0, rem = x;
    while (rem >= i + 1) { rem -= i + 1; ++i; }
    int j = rem;                       // tile (i, j), j <= i
    const unsigned short* zb = qr + (long)z * T_ * NL_;
    const unsigned short* Ab = zb + (long)(i * 128) * NL_;
    const unsigned short* Bb = zb + (long)(j * 128) * NL_;
    __shared__ unsigned short As[128][32];
    __shared__ unsigned short Bs[128][32];
    TILE_IDS
    v4f acc[4][4] = {};
    for (int k0 = 0; k0 < NL_; k0 += 32) {
        g2l16(Ab + (long)r0 * NL_ + k0 + c0, (char*)As + (wid * 2 + 0) * 1024);
        g2l16(Ab + (long)r1 * NL_ + k0 + c1, (char*)As + (wid * 2 + 1) * 1024);
        g2l16(Bb + (long)r0 * NL_ + k0 + c0, (char*)Bs + (wid * 2 + 0) * 1024);
        g2l16(Bb + (long)r1 * NL_ + k0 + c1, (char*)Bs + (wid * 2 + 1) * 1024);
        __syncthreads();
        TILE_MFMA(As, Bs)
        __syncthreads();
    }
    unsigned short* ob = Sp + (long)z * STILE + (long)x * 16384;
    bool diag = (i == j);
    #pragma unroll
    for (int r = 0; r < 4; ++r)
        #pragma unroll
        for (int c = 0; c < 4; ++c)
            #pragma unroll
            for (int e = 0; e < 4; ++e) {
                int row = wm + r * 16 + q * 4 + e;
                int col = wn + c * 16 + ln16;
                float v = acc[r][c][e];
                if (diag && row <= col) v = 0.f;   // strict causal
                ob[row * 128 + col] = f2b(v);
            }
}

// ---------------------------------------------------------------------------
// PX512 v2: yKV = LN(S @ xs) fused.  64-row strip x FULL D=512 per block,
// double-buffered staging (next round's global_load_lds issued BEFORE the
// current round's compute, drained by the trailing barrier), fused two-pass
// LayerNorm in the epilogue (block owns complete rows).
// grid (16 z, 32 my): z fastest -> XCD pin; my = 31-by heavy-first.
// LDS: As 2x4KB + Xs 2x32KB = 72 KB -> 2 blocks/CU.
__global__ __launch_bounds__(256) void px512(const unsigned short* __restrict__ Sp,
                                             const unsigned short* __restrict__ xsT,
                                             unsigned short* __restrict__ ykv) {
    int z = blockIdx.x;
    int my = 31 - blockIdx.y;          // 64-row strip, heavy first
    int b = z >> 3, h = z & 7;
    int ti = my >> 1;                  // 128-tile row
    const unsigned short* Ab = Sp + (long)z * STILE +
                               (long)(ti * (ti + 1) / 2) * 16384 +
                               (long)(my & 1) * 64 * 128;
    const unsigned short* Xb = xsT + (long)b * D_ * T_;
    __shared__ unsigned short As[2][64 * 32];    //  8 KB
    __shared__ unsigned short Xs[2][512 * 32];   // 64 KB
    int tid = threadIdx.x;
    int lane = tid & 63, wid = tid >> 6;
    int ln16 = lane & 15, q = lane >> 4;
    int srl = lane >> 2, scl = (lane & 3) * 8;
    v4f yacc[4][8] = {};
    int rounds = (ti + 1) * 4;         // kend / 32

    auto stage = [&](int r, int bf) {
        int k0 = r * 32;
        const unsigned short* At = Ab + ((long)(k0 >> 7) << 14);
        int kc = k0 & 127;
        g2l16(At + (wid * 16 + srl) * 128 + kc + scl,
              (char*)&As[bf][0] + wid * 1024);
        #pragma unroll
        for (int i = 0; i < 8; ++i) {
            int c = wid * 8 + i;
            int dr = c * 16 + srl;
            g2l16(Xb + (long)dr * T_ + k0 + scl, (char*)&Xs[bf][0] + c * 1024);
        }
    };

    stage(0, 0);
    __syncthreads();
    for (int r = 0; r < rounds; ++r) {
        int cur = r & 1;
        if (r + 1 < rounds) stage(r + 1, cur ^ 1);   // in flight during compute
        const unsigned short* Ac = &As[cur][0];
        const unsigned short* Xc = &Xs[cur][0];
        v8bf af[4], xf[8];
        #pragma unroll
        for (int m = 0; m < 4; ++m)
            af[m] = *(const v8bf*)&Ac[(m * 16 + ln16) * 32 + q * 8];
        #pragma unroll
        for (int n = 0; n < 8; ++n)
            xf[n] = *(const v8bf*)&Xc[(wid * 128 + n * 16 + ln16) * 32 + q * 8];
        #pragma unroll
        for (int m = 0; m < 4; ++m)
            #pragma unroll
            for (int n = 0; n < 8; ++n)
                yacc[m][n] = __builtin_amdgcn_mfma_f32_16x16x32_bf16(
                    af[m], xf[n], yacc[m][n], 0, 0, 0);
        __syncthreads();   // drains next-round loads + protects buffer reuse
    }

    // ---- fused LayerNorm (two-pass, centered) over the 512-wide rows ----
    // row rloc = m*16 + q*4 + e; cols spread over wid(4) x n(8) x ln16(16).
    float* red = (float*)&Xs[0][0];    // reuse LDS: [64 rows][4 waves]
    float mu[4][4], inv[4][4];
    #pragma unroll
    for (int m = 0; m < 4; ++m)
        #pragma unroll
        for (int e = 0; e < 4; ++e) {
            float p = 0.f;
            #pragma unroll
            for (int n = 0; n < 8; ++n) p += yacc[m][n][e];
            #pragma unroll
            for (int off = 1; off < 16; off <<= 1) p += __shfl_xor(p, off, 64);
            if (ln16 == 0) red[(m * 16 + q * 4 + e) * 4 + wid] = p;
        }
    __syncthreads();
    #pragma unroll
    for (int m = 0; m < 4; ++m)
        #pragma unroll
        for (int e = 0; e < 4; ++e) {
            int rl = (m * 16 + q * 4 + e) * 4;
            mu[m][e] = (red[rl] + red[rl + 1] + red[rl + 2] + red[rl + 3]) *
                       (1.0f / 512.0f);
        }
    __syncthreads();
    #pragma unroll
    for (int m = 0; m < 4; ++m)
        #pragma unroll
        for (int e = 0; e < 4; ++e) {
            float p = 0.f;
            #pragma unroll
            for (int n = 0; n < 8; ++n) {
                float d = yacc[m][n][e] - mu[m][e];
                p += d * d;
            }
            #pragma unroll
            for (int off = 1; off < 16; off <<= 1) p += __shfl_xor(p, off, 64);
            if (ln16 == 0) red[(m * 16 + q * 4 + e) * 4 + wid] = p;
        }
    __syncthreads();
    #pragma unroll
    for (int m = 0; m < 4; ++m)
        #pragma unroll
        for (int e = 0; e < 4; ++e) {
            int rl = (m * 16 + q * 4 + e) * 4;
            float var = (red[rl] + red[rl + 1] + red[rl + 2] + red[rl + 3]) *
                        (1.0f / 512.0f);
            inv[m][e] = rsqrtf(var + 1e-5f);
        }
    #pragma unroll
    for (int m = 0; m < 4; ++m)
        #pragma unroll
        for (int n = 0; n < 8; ++n)
            #pragma unroll
            for (int e = 0; e < 4; ++e) {
                int t = my * 64 + m * 16 + q * 4 + e;
                int d = wid * 128 + n * 16 + ln16;
                float v = (yacc[m][n][e] - mu[m][e]) * inv[m][e];
                ykv[((long)h * BT_ + (long)b * T_ + t) * D_ + d] = f2b(v);
            }
}

// ---------------------------------------------------------------------------
// Transpose + cast fp32 -> bf16: out[Cc][R] = (bf16) in[R][Cc], batched.
__global__ __launch_bounds__(256) void trans_cast(
    const float* __restrict__ in, long sIn, unsigned short* __restrict__ out,
    long sOut, int R, int Cc) {
    __shared__ float tl[32][33];
    int z = blockIdx.z;
    int r0 = blockIdx.y * 32, c0 = blockIdx.x * 32;
    int tx = threadIdx.x & 31, ty = threadIdx.x >> 5;
    const float* ip = in + (long)z * sIn;
    unsigned short* op = out + (long)z * sOut;
    #pragma unroll
    for (int j = 0; j < 4; ++j)
        tl[ty + j * 8][tx] = ip[(long)(r0 + ty + j * 8) * Cc + c0 + tx];
    __syncthreads();
    #pragma unroll
    for (int j = 0; j < 4; ++j)
        op[(long)(c0 + ty + j * 8) * R + r0 + tx] = f2b(tl[tx][ty + j * 8]);
}

// fp32 -> bf16 elementwise (n multiple of 1024)
__global__ __launch_bounds__(256) void cast_b(const float* __restrict__ in,
                                              unsigned short* __restrict__ out) {
    long i = ((long)blockIdx.x * 256 + threadIdx.x) * 4;
    float4 v = *(const float4*)&in[i];
    ushort4 o;
    o.x = f2b(v.x); o.y = f2b(v.y); o.z = f2b(v.z); o.w = f2b(v.w);
    *(ushort4*)&out[i] = o;
}

// out = t0+t1+t2+t3 + bias (4 split-K slices, rows of 512)
__global__ __launch_bounds__(256) void add_out4(const float* __restrict__ t,
                                                long slice,
                                                const float* __restrict__ bias,
                                                float* __restrict__ o) {
    long i = ((long)blockIdx.x * 256 + threadIdx.x) * 4;
    float4 v0 = *(const float4*)&t[i];
    float4 v1 = *(const float4*)&t[i + slice];
    float4 v2 = *(const float4*)&t[i + 2 * slice];
    float4 v3 = *(const float4*)&t[i + 3 * slice];
    float4 bv = *(const float4*)&bias[i & 511];
    float4 r;
    r.x = v0.x + v1.x + v2.x + v3.x + bv.x;
    r.y = v0.y + v1.y + v2.y + v3.y + bv.y;
    r.z = v0.z + v1.z + v2.z + v3.z + bv.z;
    r.w = v0.w + v1.w + v2.w + v3.w + bv.w;
    *(float4*)&o[i] = r;
}

// ---------------------------------------------------------------------------
// RoPE: xsp [BT][HN] bf16 -> qr [B][NH][T][NL] bf16 (head-outer layout).
__global__ __launch_bounds__(256) void rope_b(const unsigned short* __restrict__ xsp,
                                              unsigned short* __restrict__ qr) {
    long i = (long)blockIdx.x * 256 + threadIdx.x;  // group of 4 pairs
    int g = (int)(i & 255);
    long row = i >> 8;
    int h = g >> 5, n8 = g & 31;
    long b = row >> 11;
    int t = (int)(row & (T_ - 1));
    us8 u = *(const us8*)&xsp[row * HN_ + (long)g * 8];
    us8 o;
    #pragma unroll
    for (int p = 0; p < 4; ++p) {
        int n2 = n8 * 4 + p;
        float f = exp2f(-(float)n2 * 0.125f) * (float)(1.0 / (2.0 * M_PI));
        float ph = (float)t * f;
        ph = (ph - floorf(ph)) * (float)(2.0 * M_PI);
        float s, c;
        __sincosf(ph, &s, &c);
        float x0 = b2f(u[2 * p]), x1 = b2f(u[2 * p + 1]);
        o[2 * p]     = f2b(x0 * c - x1 * s);
        o[2 * p + 1] = f2b(x1 * c + x0 * s);
    }
    long ob = (((b * NH_ + h) * T_ + t) * NL_) + (long)n8 * 8;
    *(us8*)&qr[ob] = o;
}

// ---------------------------------------------------------------------------
// LayerNorm helpers (rows of 512, 256 threads, float2 per thread)
__device__ inline float2 block_reduce2(float a, float b) {
    __shared__ float sa[4], sb[4];
    #pragma unroll
    for (int off = 32; off; off >>= 1) {
        a += __shfl_down(a, off, 64);
        b += __shfl_down(b, off, 64);
    }
    __syncthreads();
    int w = threadIdx.x >> 6;
    if ((threadIdx.x & 63) == 0) { sa[w] = a; sb[w] = b; }
    __syncthreads();
    return make_float2(sa[0] + sa[1] + sa[2] + sa[3],
                       sb[0] + sb[1] + sb[2] + sb[3]);
}
__device__ inline float2 ln_pair(float2 v) {
    float2 s = block_reduce2(v.x + v.y, 0.f);
    float mu = s.x * (1.0f / 512.0f);
    float dx = v.x - mu, dy = v.y - mu;
    float2 q = block_reduce2(dx * dx + dy * dy, 0.f);
    float inv = rsqrtf(q.x * (1.0f / 512.0f) + 1e-5f);
    return make_float2(dx * inv, dy * inv);
}

// LN(sum of 4 slices + bias) -> fp32 + bf16
__global__ __launch_bounds__(256) void ln_dual4(const float* __restrict__ t,
                                                long slice,
                                                const float* __restrict__ bias,
                                                float* __restrict__ outf,
                                                unsigned short* __restrict__ outb) {
    long row = blockIdx.x;
    int c = threadIdx.x * 2;
    long i = row * 512 + c;
    float2 v0 = *(const float2*)&t[i];
    float2 v1 = *(const float2*)&t[i + slice];
    float2 v2 = *(const float2*)&t[i + 2 * slice];
    float2 v3 = *(const float2*)&t[i + 3 * slice];
    float2 bv = *(const float2*)&bias[c];
    float2 v = make_float2(v0.x + v1.x + v2.x + v3.x + bv.x,
                           v0.y + v1.y + v2.y + v3.y + bv.y);
    float2 o = ln_pair(v);
    *(float2*)&outf[i] = o;
    ushort2 ob; ob.x = f2b(o.x); ob.y = f2b(o.y);
    *(ushort2*)&outb[i] = ob;
}

// xs_next = LN(x_res + LN(sum of 4 ymlp slices)) -> fp32 + bf16
__global__ __launch_bounds__(256) void combine_dual4(
    const float* __restrict__ t, long slice, const float* __restrict__ xres,
    float* __restrict__ outf, unsigned short* __restrict__ outb) {
    long row = blockIdx.x;
    int c = threadIdx.x * 2;
    long i = row * 512 + c;
    float2 v0 = *(const float2*)&t[i];
    float2 v1 = *(const float2*)&t[i + slice];
    float2 v2 = *(const float2*)&t[i + 2 * slice];
    float2 v3 = *(const float2*)&t[i + 3 * slice];
    float2 y = make_float2(v0.x + v1.x + v2.x + v3.x,
                           v0.y + v1.y + v2.y + v3.y);
    float2 l = ln_pair(y);
    float2 r = *(const float2*)&xres[i];
    float2 z = make_float2(r.x + l.x, r.y + l.y);
    float2 o = ln_pair(z);
    *(float2*)&outf[i] = o;
    ushort2 ob; ob.x = f2b(o.x); ob.y = f2b(o.y);
    *(ushort2*)&outb[i] = ob;
}

// ---------------------------------------------------------------------------
extern "C" void kernel_launch(void* const* d_in, const int* in_sizes, int n_in,
                              void* d_out, int out_size, void* d_ws,
                              size_t ws_size, hipStream_t stream) {
    const float* x      = (const float*)d_in[0];
    const float* w_in   = (const float*)d_in[1];
    const float* b_in   = (const float*)d_in[2];
    const float* enc    = (const float*)d_in[3];
    const float* enc_v  = (const float*)d_in[4];
    const float* dec    = (const float*)d_in[5];
    const float* head_w = (const float*)d_in[6];
    const float* head_b = (const float*)d_in[7];
    float* out = (float*)d_out;

    // ---- workspace (~209 MB) ----
    char* w = (char*)d_ws;
    auto alloc = [&](size_t bytes) { void* p = (void*)w; w += bytes; return p; };
    unsigned short* w_inT = (unsigned short*)alloc((size_t)512 * 512 * 2);
    unsigned short* headT = (unsigned short*)alloc((size_t)512 * 512 * 2);
    unsigned short* encT  = (unsigned short*)alloc((size_t)NH_ * NL_ * D_ * 2);
    unsigned short* encvT = (unsigned short*)alloc((size_t)NH_ * NL_ * D_ * 2);
    unsigned short* decT  = (unsigned short*)alloc((size_t)D_ * HN_ * 2);
    unsigned short* xb    = (unsigned short*)alloc((size_t)BT_ * D_ * 2);
    float*          tmp   = (float*)alloc((size_t)4 * BT_ * D_ * 4);  // 4 K-slices
    float*          xsf0  = (float*)alloc((size_t)BT_ * D_ * 4);
    float*          xsf1  = (float*)alloc((size_t)BT_ * D_ * 4);
    unsigned short* xs_b  = (unsigned short*)alloc((size_t)BT_ * D_ * 2);
    unsigned short* xsT   = (unsigned short*)alloc((size_t)B_ * D_ * T_ * 2);
    unsigned short* xsp   = (unsigned short*)alloc((size_t)BT_ * HN_ * 2);
    unsigned short* qrh   = (unsigned short*)alloc((size_t)BT_ * HN_ * 2);
    unsigned short* Sp    = (unsigned short*)alloc((size_t)16 * STILE * 2);
    unsigned short* ykv   = (unsigned short*)alloc((size_t)NH_ * BT_ * D_ * 2);
    const long SL = (long)BT_ * D_;   // split-K slice stride (elements)

    // ---- prep ----
    cast_b<<<BT_ * D_ / 1024, 256, 0, stream>>>(x, xb);
    trans_cast<<<dim3(16, 16, 1), 256, 0, stream>>>(w_in, 0, w_inT, 0, 512, 512);
    trans_cast<<<dim3(16, 16, 1), 256, 0, stream>>>(head_w, 0, headT, 0, 512, 512);
    trans_cast<<<dim3(8, 16, 8), 256, 0, stream>>>(enc, (long)D_ * NL_, encT,
                                                   (long)NL_ * D_, D_, NL_);
    trans_cast<<<dim3(8, 16, 8), 256, 0, stream>>>(enc_v, (long)D_ * NL_, encvT,
                                                   (long)NL_ * D_, D_, NL_);
    trans_cast<<<dim3(16, 64, 1), 256, 0, stream>>>(dec, 0, decT, 0, HN_, D_);

    // ---- xs = LN(x @ w_in + b_in)  (split-K=4, K=128/slice) ----
    gemm64<false, false, false>
        <<<dim3(4, 64, 4), 256, 0, stream>>>(xb, D_, 128, w_inT, D_, 128, tmp,
                                             D_, SL, nullptr, BT_, D_, 128);
    ln_dual4<<<BT_, 256, 0, stream>>>(tmp, SL, b_in, xsf0, xs_b);
    trans_cast<<<dim3(16, 64, 2), 256, 0, stream>>>(xsf0, (long)T_ * D_, xsT,
                                                    (long)D_ * T_, T_, D_);

    float* xin = xsf0;
    float* xout = xsf1;
    for (int l = 0; l < 3; ++l) {
        // x_sparse = relu(xs @ enc) -> bf16 [BT][HN]
        gemm64<true, false, true>
            <<<dim3(16, 64, 1), 256, 0, stream>>>(
                xs_b, D_, 0, encT, D_, 0, xsp, HN_, 0, nullptr, BT_, HN_, D_);
        // QR = rope(x_sparse) -> [B][NH][T][NL]
        rope_b<<<BT_ * HN_ / 8 / 256, 256, 0, stream>>>(xsp, qrh);
        // S = strict_tril(QR QR^T), packed tiles, z XCD-pinned
        s_gemm<<<dim3(16, NTRI), 256, 0, stream>>>(qrh, Sp);
        // yKV = LN(S @ xs) — double-buffered, LN fused in epilogue
        px512<<<dim3(16, 32), 256, 0, stream>>>(Sp, xsT, ykv);
        // xy = relu(yKV[h] @ enc_v[h]) * x_sparse — per-head batched
        gemm64<true, true, true>
            <<<dim3(2, 64, 8), 256, 0, stream>>>(
                ykv, D_, (long)BT_ * D_, encvT, D_, (long)NL_ * D_, xsp, HN_,
                NL_, xsp, BT_, NL_, D_);
        // yMLP = xy @ decoder  (split-K=4, K=512/slice) -> fp32 slices
        gemm64<false, false, false>
            <<<dim3(4, 64, 4), 256, 0, stream>>>(
                xsp, HN_, 512, decT, HN_, 512, tmp, D_, SL, nullptr, BT_, D_,
                512);
        // xs = LN(x_res + LN(yMLP))
        combine_dual4<<<BT_, 256, 0, stream>>>(tmp, SL, xin, xout, xs_b);
        trans_cast<<<dim3(16, 64, 2), 256, 0, stream>>>(xout, (long)T_ * D_,
                                                        xsT, (long)D_ * T_, T_,
                                                        D_);
        float* t = xin; xin = xout; xout = t;
    }

    // logits = xs @ head_w + head_b  (split-K=4)
    gemm64<false, false, false>
        <<<dim3(4, 64, 4), 256, 0, stream>>>(xs_b, D_, 128, headT, D_, 128, tmp,
                                             D_, SL, nullptr, BT_, D_, 128);
    add_out4<<<BT_ * 512 / 1024, 256, 0, stream>>>(tmp, SL, head_b, out);
}